// Round 1
// baseline (498.138 us; speedup 1.0000x reference)
//
#include <hip/hip_runtime.h>
#include <math.h>

#define NEG_SLOPE 0.2f

__device__ __forceinline__ float leaky(float v){ return v > 0.f ? v : NEG_SLOPE * v; }

// ---------------- CSR build ----------------
__global__ void k_hist(const int* __restrict__ dst, int E, int* __restrict__ deg){
  int i = blockIdx.x * blockDim.x + threadIdx.x;
  if (i < E) atomicAdd(&deg[dst[i]], 1);
}

// single-block exclusive scan: rowptr[0]=0, rowptr[i+1]=sum(deg[0..i])
__global__ void k_scan(const int* __restrict__ deg, int* __restrict__ rowptr, int N){
  __shared__ int wsum[16];
  __shared__ int carry;
  int tid = threadIdx.x;
  if (tid == 0) carry = 0;
  __syncthreads();
  for (int base = 0; base < N; base += 1024){
    int i = base + tid;
    int v = (i < N) ? deg[i] : 0;
    int lane = tid & 63;
    int wv = tid >> 6;
    int x = v;
    #pragma unroll
    for (int off = 1; off < 64; off <<= 1){
      int y = __shfl_up(x, off, 64);
      if (lane >= off) x += y;
    }
    if (lane == 63) wsum[wv] = x;
    __syncthreads();
    if (tid < 16){
      int y = wsum[tid];
      #pragma unroll
      for (int off = 1; off < 16; off <<= 1){
        int z = __shfl_up(y, off, 64);
        if (tid >= off) y += z;
      }
      wsum[tid] = y;
    }
    __syncthreads();
    int incl = x + ((wv > 0) ? wsum[wv - 1] : 0) + carry;
    if (i < N) rowptr[i + 1] = incl;
    __syncthreads();
    if (tid == 1023) carry = incl;
    __syncthreads();
  }
  if (tid == 0) rowptr[0] = 0;
}

__global__ void k_fill(const int* __restrict__ src, const int* __restrict__ dst, int E,
                       const int* __restrict__ rowptr, int* __restrict__ fill,
                       int* __restrict__ esrc){
  int i = blockIdx.x * blockDim.x + threadIdx.x;
  if (i < E){
    int d = dst[i];
    int pos = rowptr[d] + atomicAdd(&fill[d], 1);
    esrc[pos] = src[i];
  }
}

// ---------------- GEMM1: xh = x @ W1, fused s,t logits ----------------
// M=N_nodes, K=128, N=512. Tile 128x128, K-tile 32, 256 threads, 8x8/thread.
#define GBM 128
#define GBN 128
#define GKT 32

__global__ __launch_bounds__(256) void k_gemm1(
    const float* __restrict__ x, const float* __restrict__ W1,
    const float* __restrict__ asrc, const float* __restrict__ adst,
    float* __restrict__ xh, float* __restrict__ s, float* __restrict__ t, int N)
{
  __shared__ float xs[GBM][GKT + 4];   // stride 36 floats: rows r,r+1 -> banks +4 (conflict-free)
  __shared__ float wsm[GKT][GBN];
  int m0 = blockIdx.x * GBM;
  int c0 = blockIdx.y * GBN;           // covers heads c0/64, c0/64+1
  int tid = threadIdx.x;
  int ty = tid >> 4, tx = tid & 15;
  float acc[8][8] = {};

  for (int kt = 0; kt < 128; kt += GKT){
    #pragma unroll
    for (int it = 0; it < 4; ++it){
      int idx = tid + it * 256;        // 1024 float4
      int r = idx >> 3;                // 0..127
      int c4 = (idx & 7) << 2;         // 0..28
      float4 v = make_float4(0.f, 0.f, 0.f, 0.f);
      if (m0 + r < N) v = *(const float4*)(x + (size_t)(m0 + r) * 128 + kt + c4);
      xs[r][c4 + 0] = v.x; xs[r][c4 + 1] = v.y; xs[r][c4 + 2] = v.z; xs[r][c4 + 3] = v.w;
    }
    #pragma unroll
    for (int it = 0; it < 4; ++it){
      int idx = tid + it * 256;
      int r = idx >> 5;                // 0..31
      int c4 = (idx & 31) << 2;        // 0..124
      *(float4*)&wsm[r][c4] = *(const float4*)(W1 + (size_t)(kt + r) * 512 + c0 + c4);
    }
    __syncthreads();
    #pragma unroll
    for (int k4 = 0; k4 < GKT; k4 += 4){
      float4 xa[8];
      #pragma unroll
      for (int i = 0; i < 8; ++i) xa[i] = *(float4*)&xs[i * 16 + ty][k4];
      #pragma unroll
      for (int kk = 0; kk < 4; ++kk){
        float4 wa0 = *(float4*)&wsm[k4 + kk][tx * 4];          // lanes stride 16B: 2-way, free
        float4 wa1 = *(float4*)&wsm[k4 + kk][64 + tx * 4];
        float wv[8] = {wa0.x, wa0.y, wa0.z, wa0.w, wa1.x, wa1.y, wa1.z, wa1.w};
        #pragma unroll
        for (int i = 0; i < 8; ++i){
          float xv = ((const float*)&xa[i])[kk];
          #pragma unroll
          for (int j = 0; j < 8; ++j) acc[i][j] += xv * wv[j];
        }
      }
    }
    __syncthreads();
  }

  // epilogue: store xh, fused s/t (two heads per block, exact reduction over 16 tx lanes)
  int hbase = c0 >> 6;
  #pragma unroll
  for (int i = 0; i < 8; ++i){
    int node = m0 + i * 16 + ty;
    float s0 = 0.f, t0 = 0.f, s1 = 0.f, t1 = 0.f;
    #pragma unroll
    for (int j = 0; j < 4; ++j){
      float a0 = asrc[hbase * 64 + tx * 4 + j];
      float d0 = adst[hbase * 64 + tx * 4 + j];
      float a1 = asrc[(hbase + 1) * 64 + tx * 4 + j];
      float d1 = adst[(hbase + 1) * 64 + tx * 4 + j];
      s0 += acc[i][j] * a0;     t0 += acc[i][j] * d0;
      s1 += acc[i][4 + j] * a1; t1 += acc[i][4 + j] * d1;
    }
    #pragma unroll
    for (int off = 1; off < 16; off <<= 1){
      s0 += __shfl_xor(s0, off, 64);
      t0 += __shfl_xor(t0, off, 64);
      s1 += __shfl_xor(s1, off, 64);
      t1 += __shfl_xor(t1, off, 64);
    }
    if (node < N){
      *(float4*)(xh + (size_t)node * 512 + c0 + tx * 4) =
          make_float4(acc[i][0], acc[i][1], acc[i][2], acc[i][3]);
      *(float4*)(xh + (size_t)node * 512 + c0 + 64 + tx * 4) =
          make_float4(acc[i][4], acc[i][5], acc[i][6], acc[i][7]);
      if (tx == 0){
        s[node * 8 + hbase] = s0;     t[node * 8 + hbase] = t0;
        s[node * 8 + hbase + 1] = s1; t[node * 8 + hbase + 1] = t1;
      }
    }
  }
}

// ---------------- agg1: per-dst softmax + message aggregation + fused layer-2 projection ----
// block = 256 threads per dst node; thread owns channels 2*tid, 2*tid+1.
__global__ __launch_bounds__(256) void k_agg1(
    const float* __restrict__ xh, const float* __restrict__ s, const float* __restrict__ t,
    const int* __restrict__ rowptr, const int* __restrict__ esrc,
    const float* __restrict__ b1, const float* __restrict__ W2,
    float* __restrict__ xh2, int N)
{
  __shared__ float red_m[32], red_d[32];
  __shared__ float emax_s[8], den_s[8], ts[8], ss[8];
  __shared__ int   srcs[32];
  __shared__ float alph[32][8];
  __shared__ float wred[4];

  int n = blockIdx.x;
  int tid = threadIdx.x;
  int row0 = rowptr[n], row1 = rowptr[n + 1];
  int deg = row1 - row0;

  // ---- phase A: online (max, denom) over incoming edges + self loop ----
  int h = tid & 7;
  int es = tid >> 3;                      // 0..31
  float tn = t[n * 8 + h];
  float sn = s[n * 8 + h];
  float m = -INFINITY, d = 0.f;
  if (es == 0){
    m = leaky(sn + tn);                   // self loop
    d = 1.f;
    ts[h] = tn; ss[h] = sn;
  }
  for (int e = es; e < deg; e += 32){
    int src = esrc[row0 + e];
    float v = leaky(s[src * 8 + h] + tn);
    if (v <= m) d += __expf(v - m);
    else { d = d * __expf(m - v) + 1.f; m = v; }
  }
  #pragma unroll
  for (int off = 8; off < 64; off <<= 1){ // combine lanes sharing h within wave
    float m2 = __shfl_xor(m, off, 64);
    float d2 = __shfl_xor(d, off, 64);
    float M = fmaxf(m, m2);
    d = (M == -INFINITY) ? 0.f : (d * __expf(m - M) + d2 * __expf(m2 - M));
    m = M;
  }
  int wv = tid >> 6;
  if ((tid & 63) < 8){ red_m[wv * 8 + h] = m; red_d[wv * 8 + h] = d; }
  __syncthreads();
  if (tid < 8){
    float M = red_m[tid], D = red_d[tid];
    #pragma unroll
    for (int w2 = 1; w2 < 4; ++w2){
      float m2 = red_m[w2 * 8 + tid], d2 = red_d[w2 * 8 + tid];
      float MM = fmaxf(M, m2);
      D = D * __expf(M - MM) + d2 * __expf(m2 - MM);
      M = MM;
    }
    emax_s[tid] = M; den_s[tid] = D;
  }
  __syncthreads();

  // ---- phase B: out[c] = sum_e alpha_e * xh[src_e][c]  (c = 2*tid, 2*tid+1) ----
  int h0 = tid >> 5;                      // head of both owned channels
  float em0 = emax_s[h0], dn0 = den_s[h0];
  float a_self = __expf(leaky(ss[h0] + ts[h0]) - em0) / dn0;
  const float2* xrn = (const float2*)(xh + (size_t)n * 512);
  float2 xv = xrn[tid];
  float acc0 = a_self * xv.x;
  float acc1 = a_self * xv.y;

  int he = tid & 7;                       // layout for alpha computation
  int ee = tid >> 3;
  float tne = ts[he], eme = emax_s[he], dne = den_s[he];

  for (int base = 0; base < deg; base += 32){
    int cnt = min(32, deg - base);
    __syncthreads();
    if (ee < cnt){
      int src = esrc[row0 + base + ee];
      if (he == 0) srcs[ee] = src;
      alph[ee][he] = __expf(leaky(s[src * 8 + he] + tne) - eme) / dne;
    }
    __syncthreads();
    for (int j = 0; j < cnt; ++j){
      const float2* xr = (const float2*)(xh + (size_t)srcs[j] * 512);
      float a = alph[j][h0];
      float2 v = xr[tid];
      acc0 += a * v.x;
      acc1 += a * v.y;
    }
  }

  // ---- epilogue: h = relu(out + b1); xh2[n] = h . W2  (never materialize h) ----
  const float2* b1v = (const float2*)b1;
  const float2* W2v = (const float2*)W2;
  float2 bb = b1v[tid], ww = W2v[tid];
  float o0 = acc0 + bb.x; o0 = o0 > 0.f ? o0 : 0.f;
  float o1 = acc1 + bb.y; o1 = o1 > 0.f ? o1 : 0.f;
  float p = o0 * ww.x + o1 * ww.y;
  #pragma unroll
  for (int off = 1; off < 64; off <<= 1) p += __shfl_xor(p, off, 64);
  if ((tid & 63) == 0) wred[tid >> 6] = p;
  __syncthreads();
  if (tid == 0) xh2[n] = wred[0] + wred[1] + wred[2] + wred[3];
}

// ---------------- agg2: scalar GAT layer (H=1,C=1), online softmax per node -----------
__global__ void k_agg2(const float* __restrict__ xh2, const int* __restrict__ rowptr,
                       const int* __restrict__ esrc,
                       const float* __restrict__ as2p, const float* __restrict__ ad2p,
                       const float* __restrict__ b2p,
                       float* __restrict__ out, int N)
{
  int n = blockIdx.x * blockDim.x + threadIdx.x;
  if (n >= N) return;
  float a_s = as2p[0], a_d = ad2p[0], b2 = b2p[0];
  float xn = xh2[n];
  float t2 = a_d * xn;
  float m = leaky(a_s * xn + t2);         // self loop
  float den = 1.f, num = xn;
  int row0 = rowptr[n], row1 = rowptr[n + 1];
  for (int e = row0; e < row1; ++e){
    int src = esrc[e];
    float xs2 = xh2[src];
    float ev = leaky(a_s * xs2 + t2);
    if (ev <= m){
      float w = __expf(ev - m);
      den += w; num += w * xs2;
    } else {
      float f = __expf(m - ev);
      den = den * f + 1.f;
      num = num * f + xs2;
      m = ev;
    }
  }
  out[n] = num / den + b2;
}

extern "C" void kernel_launch(void* const* d_in, const int* in_sizes, int n_in,
                              void* d_out, int out_size, void* d_ws, size_t ws_size,
                              hipStream_t stream) {
  const float* x   = (const float*)d_in[0];
  const int*   ei  = (const int*)d_in[1];
  const float* W1  = (const float*)d_in[2];
  const float* as1 = (const float*)d_in[3];
  const float* ad1 = (const float*)d_in[4];
  const float* b1  = (const float*)d_in[5];
  const float* W2  = (const float*)d_in[6];
  const float* as2 = (const float*)d_in[7];
  const float* ad2 = (const float*)d_in[8];
  const float* b2  = (const float*)d_in[9];
  float* out = (float*)d_out;

  int N = in_sizes[0] / 128;
  int E = in_sizes[1] / 2;
  const int* src_in = ei;
  const int* dst_in = ei + E;

  char* w = (char*)d_ws;
  auto alloc = [&](size_t bytes){ void* p = (void*)w; w += (bytes + 255) & ~(size_t)255; return p; };
  float* xh     = (float*)alloc((size_t)N * 512 * 4);
  float* s      = (float*)alloc((size_t)N * 8 * 4);
  float* t      = (float*)alloc((size_t)N * 8 * 4);
  float* xh2    = (float*)alloc((size_t)N * 4);
  int*   deg    = (int*)alloc((size_t)N * 4);
  int*   rowptr = (int*)alloc((size_t)(N + 1) * 4);
  int*   fill   = (int*)alloc((size_t)N * 4);
  int*   esrc   = (int*)alloc((size_t)E * 4);

  hipMemsetAsync(deg, 0, (size_t)N * 4, stream);
  hipMemsetAsync(fill, 0, (size_t)N * 4, stream);
  k_hist<<<(E + 255) / 256, 256, 0, stream>>>(dst_in, E, deg);
  k_scan<<<1, 1024, 0, stream>>>(deg, rowptr, N);
  k_fill<<<(E + 255) / 256, 256, 0, stream>>>(src_in, dst_in, E, rowptr, fill, esrc);
  k_gemm1<<<dim3((N + 127) / 128, 4), 256, 0, stream>>>(x, W1, as1, ad1, xh, s, t, N);
  k_agg1<<<N, 256, 0, stream>>>(xh, s, t, rowptr, esrc, b1, W2, xh2, N);
  k_agg2<<<(N + 255) / 256, 256, 0, stream>>>(xh2, rowptr, esrc, as2, ad2, b2, out, N);
}

// Round 2
// 374.236 us; speedup vs baseline: 1.3311x; 1.3311x over previous
//
#include <hip/hip_runtime.h>
#include <math.h>

#define NEG_SLOPE 0.2f

__device__ __forceinline__ float leaky(float v){ return v > 0.f ? v : NEG_SLOPE * v; }

// round-to-nearest-even f32 -> bf16 (values are finite; no NaN handling needed)
static __device__ __forceinline__ unsigned int f2bf(float x){
  unsigned u = __float_as_uint(x);
  return (u + 0x7fffu + ((u >> 16) & 1u)) >> 16;
}

// ---------------- CSR build ----------------
__global__ void k_hist(const int* __restrict__ dst, int E, int* __restrict__ deg){
  int i = blockIdx.x * blockDim.x + threadIdx.x;
  if (i < E) atomicAdd(&deg[dst[i]], 1);
}

// hierarchical scan: scan1 (per-256 block inclusive), scan2 (block sums), scan3 (combine)
__global__ void k_scan1(const int* __restrict__ deg, int* __restrict__ tmp,
                        int* __restrict__ bsum, int N){
  __shared__ int ws[4];
  int tid = threadIdx.x;
  int i = blockIdx.x * 256 + tid;
  int v = (i < N) ? deg[i] : 0;
  int lane = tid & 63, wv = tid >> 6;
  int x = v;
  #pragma unroll
  for (int off = 1; off < 64; off <<= 1){
    int y = __shfl_up(x, off, 64);
    if (lane >= off) x += y;
  }
  if (lane == 63) ws[wv] = x;
  __syncthreads();
  int p = 0;
  for (int w = 0; w < wv; ++w) p += ws[w];
  x += p;
  if (i < N) tmp[i] = x;
  if (tid == 255) bsum[blockIdx.x] = x;
}

__global__ void k_scan2(int* __restrict__ bsum, int nb){
  __shared__ int ws[4];
  int tid = threadIdx.x;
  int v = (tid < nb) ? bsum[tid] : 0;
  int lane = tid & 63, wv = tid >> 6;
  int x = v;
  #pragma unroll
  for (int off = 1; off < 64; off <<= 1){
    int y = __shfl_up(x, off, 64);
    if (lane >= off) x += y;
  }
  if (lane == 63) ws[wv] = x;
  __syncthreads();
  int p = 0;
  for (int w = 0; w < wv; ++w) p += ws[w];
  x += p;
  if (tid < nb) bsum[tid] = x;
}

__global__ void k_scan3(const int* __restrict__ tmp, const int* __restrict__ bsum,
                        int* __restrict__ rowptr, int N){
  int i = blockIdx.x * 256 + threadIdx.x;
  if (i < N) rowptr[i + 1] = tmp[i] + (blockIdx.x ? bsum[blockIdx.x - 1] : 0);
  if (i == 0) rowptr[0] = 0;
}

__global__ void k_fill(const int* __restrict__ src, const int* __restrict__ dst, int E,
                       const int* __restrict__ rowptr, int* __restrict__ fill,
                       int* __restrict__ esrc){
  int i = blockIdx.x * blockDim.x + threadIdx.x;
  if (i < E){
    int d = dst[i];
    int pos = rowptr[d] + atomicAdd(&fill[d], 1);
    esrc[pos] = src[i];
  }
}

// ---------------- logit weights: wst[k][0..7]=W1.a_src per head, [8..15]=W1.a_dst ----
__global__ void k_w1a(const float* __restrict__ W1, const float* __restrict__ as,
                      const float* __restrict__ ad, float* __restrict__ wst){
  int t = threadIdx.x;
  int k = t & 127, half = t >> 7;
  const float* a = half ? ad : as;
  for (int h = 0; h < 8; ++h){
    float sum = 0.f;
    for (int c = 0; c < 64; ++c) sum += W1[(size_t)k * 512 + h * 64 + c] * a[h * 64 + c];
    wst[k * 16 + half * 8 + h] = sum;
  }
}

// ---------------- logits: [s|t](n,h) = x(n,:) . wst(:,o)  — exact fp32 ----------------
__global__ __launch_bounds__(256) void k_logits(const float* __restrict__ x,
                                                const float* __restrict__ wst,
                                                float* __restrict__ s, float* __restrict__ t,
                                                int N){
  __shared__ float xs[64][132];
  __shared__ float wl[2048];
  int tid = threadIdx.x;
  int n0 = blockIdx.x * 64;
  for (int i = tid; i < 2048; i += 256) wl[i] = wst[i];
  for (int i = tid; i < 2048; i += 256){
    int r = i >> 5, c4 = (i & 31) << 2;
    float4 v = make_float4(0.f, 0.f, 0.f, 0.f);
    if (n0 + r < N) v = *(const float4*)(x + (size_t)(n0 + r) * 128 + c4);
    xs[r][c4 + 0] = v.x; xs[r][c4 + 1] = v.y; xs[r][c4 + 2] = v.z; xs[r][c4 + 3] = v.w;
  }
  __syncthreads();
  int node = tid & 63, og = tid >> 6;
  float a0 = 0.f, a1 = 0.f, a2 = 0.f, a3 = 0.f;
  int o = og * 4;
  for (int k = 0; k < 128; ++k){
    float v = xs[node][k];
    a0 += v * wl[k * 16 + o + 0];
    a1 += v * wl[k * 16 + o + 1];
    a2 += v * wl[k * 16 + o + 2];
    a3 += v * wl[k * 16 + o + 3];
  }
  int n = n0 + node;
  if (n < N){
    if (o < 8){
      s[n * 8 + o + 0] = a0; s[n * 8 + o + 1] = a1;
      s[n * 8 + o + 2] = a2; s[n * 8 + o + 3] = a3;
    } else {
      int oo = o - 8;
      t[n * 8 + oo + 0] = a0; t[n * 8 + oo + 1] = a1;
      t[n * 8 + oo + 2] = a2; t[n * 8 + oo + 3] = a3;
    }
  }
}

// ---------------- GEMM1: xhb = bf16(x @ W1) ----------------
#define GBM 128
#define GBN 128
#define GKT 32

__global__ __launch_bounds__(256) void k_gemm1(
    const float* __restrict__ x, const float* __restrict__ W1,
    unsigned short* __restrict__ xhb, int N)
{
  __shared__ float xs[GBM][GKT + 4];
  __shared__ float wsm[GKT][GBN];
  int m0 = blockIdx.x * GBM;
  int c0 = blockIdx.y * GBN;
  int tid = threadIdx.x;
  int ty = tid >> 4, tx = tid & 15;
  float acc[8][8] = {};

  for (int kt = 0; kt < 128; kt += GKT){
    #pragma unroll
    for (int it = 0; it < 4; ++it){
      int idx = tid + it * 256;
      int r = idx >> 3;
      int c4 = (idx & 7) << 2;
      float4 v = make_float4(0.f, 0.f, 0.f, 0.f);
      if (m0 + r < N) v = *(const float4*)(x + (size_t)(m0 + r) * 128 + kt + c4);
      xs[r][c4 + 0] = v.x; xs[r][c4 + 1] = v.y; xs[r][c4 + 2] = v.z; xs[r][c4 + 3] = v.w;
    }
    #pragma unroll
    for (int it = 0; it < 4; ++it){
      int idx = tid + it * 256;
      int r = idx >> 5;
      int c4 = (idx & 31) << 2;
      *(float4*)&wsm[r][c4] = *(const float4*)(W1 + (size_t)(kt + r) * 512 + c0 + c4);
    }
    __syncthreads();
    #pragma unroll
    for (int k4 = 0; k4 < GKT; k4 += 4){
      float4 xa[8];
      #pragma unroll
      for (int i = 0; i < 8; ++i) xa[i] = *(float4*)&xs[i * 16 + ty][k4];
      #pragma unroll
      for (int kk = 0; kk < 4; ++kk){
        float4 wa0 = *(float4*)&wsm[k4 + kk][tx * 4];
        float4 wa1 = *(float4*)&wsm[k4 + kk][64 + tx * 4];
        float wv[8] = {wa0.x, wa0.y, wa0.z, wa0.w, wa1.x, wa1.y, wa1.z, wa1.w};
        #pragma unroll
        for (int i = 0; i < 8; ++i){
          float xv = ((const float*)&xa[i])[kk];
          #pragma unroll
          for (int j = 0; j < 8; ++j) acc[i][j] += xv * wv[j];
        }
      }
    }
    __syncthreads();
  }

  #pragma unroll
  for (int i = 0; i < 8; ++i){
    int node = m0 + i * 16 + ty;
    if (node < N){
      uint2 p0, p1;
      p0.x = f2bf(acc[i][0]) | (f2bf(acc[i][1]) << 16);
      p0.y = f2bf(acc[i][2]) | (f2bf(acc[i][3]) << 16);
      p1.x = f2bf(acc[i][4]) | (f2bf(acc[i][5]) << 16);
      p1.y = f2bf(acc[i][6]) | (f2bf(acc[i][7]) << 16);
      *(uint2*)(xhb + (size_t)node * 512 + c0 + tx * 4) = p0;
      *(uint2*)(xhb + (size_t)node * 512 + c0 + 64 + tx * 4) = p1;
    }
  }
}

// ---------------- agg1: wave per dst node; bf16 messages; fused relu + .W2 ----------
__global__ __launch_bounds__(256) void k_agg1(
    const uint4* __restrict__ xhb,      // [N][64] uint4 = [N][512] bf16
    const float* __restrict__ s, const float* __restrict__ t,
    const int* __restrict__ rowptr, const int* __restrict__ esrc,
    const float* __restrict__ b1, const float* __restrict__ W2,
    float* __restrict__ xh2, int N)
{
  int n = (blockIdx.x * 256 + threadIdx.x) >> 6;   // wave id = node
  if (n >= N) return;
  int lane = threadIdx.x & 63;
  int row0 = rowptr[n], deg = rowptr[n + 1] - row0;
  int h = lane & 7;

  float tn = t[(size_t)n * 8 + h];
  float sn = s[(size_t)n * 8 + h];
  float selfe = __expf(leaky(sn + tn));

  // denominators per head (no max subtraction: logits bounded, fp32-safe)
  float d = (lane < 8) ? selfe : 0.f;
  for (int e = (lane >> 3); e < deg; e += 8){
    int src = esrc[row0 + e];
    d += __expf(leaky(s[(size_t)src * 8 + h] + tn));
  }
  d += __shfl_xor(d, 8, 64);
  d += __shfl_xor(d, 16, 64);
  d += __shfl_xor(d, 32, 64);

  int H = lane >> 3;                     // head owning this lane's 8 channels
  float iden = 1.f / __shfl(d, H, 64);   // lane H (H<8) holds denom of head H

  float acc[8] = {0.f,0.f,0.f,0.f,0.f,0.f,0.f,0.f};

  // self message
  {
    float a = __shfl(selfe, H, 64) * iden;
    uint4 v = xhb[(size_t)n * 64 + lane];
    acc[0] += a * __uint_as_float(v.x << 16);
    acc[1] += a * __uint_as_float(v.x & 0xffff0000u);
    acc[2] += a * __uint_as_float(v.y << 16);
    acc[3] += a * __uint_as_float(v.y & 0xffff0000u);
    acc[4] += a * __uint_as_float(v.z << 16);
    acc[5] += a * __uint_as_float(v.z & 0xffff0000u);
    acc[6] += a * __uint_as_float(v.w << 16);
    acc[7] += a * __uint_as_float(v.w & 0xffff0000u);
  }

  for (int base = 0; base < deg; base += 8){
    int e = base + (lane >> 3);
    int srcl = 0;
    float ev = 0.f;
    if (e < deg){
      srcl = esrc[row0 + e];
      ev = __expf(leaky(s[(size_t)srcl * 8 + h] + tn));   // numer for (edge e, head h)
    }
    int cnt = min(8, deg - base);
    for (int j = 0; j < cnt; ++j){
      float a = __shfl(ev, (j << 3) | H, 64) * iden;      // alpha[edge j][head H]
      int sj = __shfl(srcl, j << 3, 64);
      uint4 v = xhb[(size_t)sj * 64 + lane];
      acc[0] += a * __uint_as_float(v.x << 16);
      acc[1] += a * __uint_as_float(v.x & 0xffff0000u);
      acc[2] += a * __uint_as_float(v.y << 16);
      acc[3] += a * __uint_as_float(v.y & 0xffff0000u);
      acc[4] += a * __uint_as_float(v.z << 16);
      acc[5] += a * __uint_as_float(v.z & 0xffff0000u);
      acc[6] += a * __uint_as_float(v.w << 16);
      acc[7] += a * __uint_as_float(v.w & 0xffff0000u);
    }
  }

  // epilogue: h = relu(acc + b1); xh2[n] = h . W2
  const float4* b1v = (const float4*)b1;
  const float4* w2v = (const float4*)W2;
  float4 b_0 = b1v[lane * 2], b_1 = b1v[lane * 2 + 1];
  float4 w_0 = w2v[lane * 2], w_1 = w2v[lane * 2 + 1];
  float p = 0.f;
  float o;
  o = acc[0] + b_0.x; o = o > 0.f ? o : 0.f; p += o * w_0.x;
  o = acc[1] + b_0.y; o = o > 0.f ? o : 0.f; p += o * w_0.y;
  o = acc[2] + b_0.z; o = o > 0.f ? o : 0.f; p += o * w_0.z;
  o = acc[3] + b_0.w; o = o > 0.f ? o : 0.f; p += o * w_0.w;
  o = acc[4] + b_1.x; o = o > 0.f ? o : 0.f; p += o * w_1.x;
  o = acc[5] + b_1.y; o = o > 0.f ? o : 0.f; p += o * w_1.y;
  o = acc[6] + b_1.z; o = o > 0.f ? o : 0.f; p += o * w_1.z;
  o = acc[7] + b_1.w; o = o > 0.f ? o : 0.f; p += o * w_1.w;
  #pragma unroll
  for (int off = 1; off < 64; off <<= 1) p += __shfl_xor(p, off, 64);
  if (lane == 0) xh2[n] = p;
}

// ---------------- agg2: scalar GAT layer (H=1,C=1) ----------------
__global__ void k_agg2(const float* __restrict__ xh2, const int* __restrict__ rowptr,
                       const int* __restrict__ esrc,
                       const float* __restrict__ as2p, const float* __restrict__ ad2p,
                       const float* __restrict__ b2p,
                       float* __restrict__ out, int N)
{
  int n = blockIdx.x * blockDim.x + threadIdx.x;
  if (n >= N) return;
  float a_s = as2p[0], a_d = ad2p[0], b2 = b2p[0];
  float xn = xh2[n];
  float t2 = a_d * xn;
  float w0 = __expf(leaky(a_s * xn + t2));     // self loop
  float den = w0, num = w0 * xn;
  int row1 = rowptr[n + 1];
  for (int e = rowptr[n]; e < row1; ++e){
    int src = esrc[e];
    float xs2 = xh2[src];
    float w = __expf(leaky(a_s * xs2 + t2));
    den += w; num += w * xs2;
  }
  out[n] = num / den + b2;
}

extern "C" void kernel_launch(void* const* d_in, const int* in_sizes, int n_in,
                              void* d_out, int out_size, void* d_ws, size_t ws_size,
                              hipStream_t stream) {
  const float* x   = (const float*)d_in[0];
  const int*   ei  = (const int*)d_in[1];
  const float* W1  = (const float*)d_in[2];
  const float* as1 = (const float*)d_in[3];
  const float* ad1 = (const float*)d_in[4];
  const float* b1  = (const float*)d_in[5];
  const float* W2  = (const float*)d_in[6];
  const float* as2 = (const float*)d_in[7];
  const float* ad2 = (const float*)d_in[8];
  const float* b2  = (const float*)d_in[9];
  float* out = (float*)d_out;

  int N = in_sizes[0] / 128;
  int E = in_sizes[1] / 2;
  const int* src_in = ei;
  const int* dst_in = ei + E;

  char* w = (char*)d_ws;
  auto alloc = [&](size_t bytes){ void* p = (void*)w; w += (bytes + 255) & ~(size_t)255; return p; };
  unsigned short* xhb = (unsigned short*)alloc((size_t)N * 512 * 2);
  float* s      = (float*)alloc((size_t)N * 8 * 4);
  float* t      = (float*)alloc((size_t)N * 8 * 4);
  float* xh2    = (float*)alloc((size_t)N * 4);
  int*   deg    = (int*)alloc((size_t)N * 4);
  int*   rowptr = (int*)alloc((size_t)(N + 1) * 4);
  int*   fill   = (int*)alloc((size_t)N * 4);
  int*   esrc   = (int*)alloc((size_t)E * 4);
  int*   tmp    = (int*)alloc((size_t)N * 4);
  int*   bsum   = (int*)alloc((size_t)1024 * 4);
  float* wst    = (float*)alloc((size_t)2048 * 4);

  int nb = (N + 255) / 256;

  hipMemsetAsync(deg, 0, (size_t)N * 4, stream);
  hipMemsetAsync(fill, 0, (size_t)N * 4, stream);
  k_hist<<<(E + 255) / 256, 256, 0, stream>>>(dst_in, E, deg);
  k_scan1<<<nb, 256, 0, stream>>>(deg, tmp, bsum, N);
  k_scan2<<<1, 256, 0, stream>>>(bsum, nb);
  k_scan3<<<nb, 256, 0, stream>>>(tmp, bsum, rowptr, N);
  k_fill<<<(E + 255) / 256, 256, 0, stream>>>(src_in, dst_in, E, rowptr, fill, esrc);
  k_w1a<<<1, 256, 0, stream>>>(W1, as1, ad1, wst);
  k_logits<<<(N + 63) / 64, 256, 0, stream>>>(x, wst, s, t, N);
  k_gemm1<<<dim3((N + 127) / 128, 4), 256, 0, stream>>>(x, W1, xhb, N);
  k_agg1<<<(N * 64 + 255) / 256, 256, 0, stream>>>((const uint4*)xhb, s, t, rowptr, esrc, b1, W2, xh2, N);
  k_agg2<<<(N + 255) / 256, 256, 0, stream>>>(xh2, rowptr, esrc, as2, ad2, b2, out, N);
}

// Round 3
// 258.335 us; speedup vs baseline: 1.9283x; 1.4486x over previous
//
#include <hip/hip_runtime.h>
#include <math.h>

#define NEG_SLOPE 0.2f

typedef __attribute__((ext_vector_type(8))) short bf16x8;
typedef __attribute__((ext_vector_type(4))) float f32x4;

__device__ __forceinline__ float leaky(float v){ return v > 0.f ? v : NEG_SLOPE * v; }

// round-to-nearest-even f32 -> bf16 bits
static __device__ __forceinline__ unsigned int f2bf(float x){
  unsigned u = __float_as_uint(x);
  return (u + 0x7fffu + ((u >> 16) & 1u)) >> 16;
}

// ---------------- CSR build ----------------
__global__ void k_hist(const int* __restrict__ dst, int E, int* __restrict__ deg){
  int i = blockIdx.x * blockDim.x + threadIdx.x;
  if (i < E) atomicAdd(&deg[dst[i]], 1);
}

__global__ void k_scan1(const int* __restrict__ deg, int* __restrict__ tmp,
                        int* __restrict__ bsum, int N){
  __shared__ int ws[4];
  int tid = threadIdx.x;
  int i = blockIdx.x * 256 + tid;
  int v = (i < N) ? deg[i] : 0;
  int lane = tid & 63, wv = tid >> 6;
  int x = v;
  #pragma unroll
  for (int off = 1; off < 64; off <<= 1){
    int y = __shfl_up(x, off, 64);
    if (lane >= off) x += y;
  }
  if (lane == 63) ws[wv] = x;
  __syncthreads();
  int p = 0;
  for (int w = 0; w < wv; ++w) p += ws[w];
  x += p;
  if (i < N) tmp[i] = x;
  if (tid == 255) bsum[blockIdx.x] = x;
}

__global__ void k_scan2(int* __restrict__ bsum, int nb){
  __shared__ int ws[4];
  int tid = threadIdx.x;
  int v = (tid < nb) ? bsum[tid] : 0;
  int lane = tid & 63, wv = tid >> 6;
  int x = v;
  #pragma unroll
  for (int off = 1; off < 64; off <<= 1){
    int y = __shfl_up(x, off, 64);
    if (lane >= off) x += y;
  }
  if (lane == 63) ws[wv] = x;
  __syncthreads();
  int p = 0;
  for (int w = 0; w < wv; ++w) p += ws[w];
  x += p;
  if (tid < nb) bsum[tid] = x;
}

__global__ void k_scan3(const int* __restrict__ tmp, const int* __restrict__ bsum,
                        int* __restrict__ rowptr, int N){
  int i = blockIdx.x * 256 + threadIdx.x;
  if (i < N) rowptr[i + 1] = tmp[i] + (blockIdx.x ? bsum[blockIdx.x - 1] : 0);
  if (i == 0) rowptr[0] = 0;
}

__global__ void k_fill(const int* __restrict__ src, const int* __restrict__ dst, int E,
                       const int* __restrict__ rowptr, int* __restrict__ fill,
                       int* __restrict__ esrc){
  int i = blockIdx.x * blockDim.x + threadIdx.x;
  if (i < E){
    int d = dst[i];
    int pos = rowptr[d] + atomicAdd(&fill[d], 1);
    esrc[pos] = src[i];
  }
}

// ---------------- weight prep: wst logit-weights; W1 packed into B-fragments (hi/lo) ----
// pack entry g = ((h*4 + ctl)*4 + kt)*64 + lane ; reg i holds
//   W1[kt*32 + (lane>>4)*8 + i][h*64 + ctl*16 + (lane&15)]
__global__ void k_wprep(const float* __restrict__ W1, const float* __restrict__ as,
                        const float* __restrict__ ad, float* __restrict__ wst,
                        bf16x8* __restrict__ packh, bf16x8* __restrict__ packl){
  int b = blockIdx.x, t = threadIdx.x;
  if (b == 0){
    int k = t & 127, half = t >> 7;
    const float* a = half ? ad : as;
    for (int h = 0; h < 8; ++h){
      float sum = 0.f;
      for (int c = 0; c < 64; ++c) sum += W1[(size_t)k * 512 + h * 64 + c] * a[h * 64 + c];
      wst[k * 16 + half * 8 + h] = sum;
    }
  } else {
    int g = (b - 1) * 256 + t;           // 0..8191
    int lane = g & 63, kt = (g >> 6) & 3, ctl = (g >> 8) & 3, h = g >> 10;
    int gc = h * 64 + ctl * 16 + (lane & 15);
    int k0 = kt * 32 + (lane >> 4) * 8;
    bf16x8 hv, lv;
    #pragma unroll
    for (int i = 0; i < 8; ++i){
      float w = W1[(size_t)(k0 + i) * 512 + gc];
      unsigned int hb = f2bf(w);
      float hf = __uint_as_float(hb << 16);
      hv[i] = (short)hb;
      lv[i] = (short)f2bf(w - hf);
    }
    packh[g] = hv; packl[g] = lv;
  }
}

// ---------------- logits (fp32 exact) + xb = bf16(x) ----------------
__global__ __launch_bounds__(256) void k_logits_xb(const float* __restrict__ x,
                                                   const float* __restrict__ wst,
                                                   float* __restrict__ s, float* __restrict__ t,
                                                   unsigned int* __restrict__ xb, int N){
  __shared__ float xs[64][132];
  __shared__ float wl[2048];
  int tid = threadIdx.x;
  int n0 = blockIdx.x * 64;
  for (int i = tid; i < 2048; i += 256) wl[i] = wst[i];
  for (int i = tid; i < 2048; i += 256){
    int r = i >> 5, c4 = (i & 31) << 2;
    float4 v = make_float4(0.f, 0.f, 0.f, 0.f);
    if (n0 + r < N) v = *(const float4*)(x + (size_t)(n0 + r) * 128 + c4);
    xs[r][c4 + 0] = v.x; xs[r][c4 + 1] = v.y; xs[r][c4 + 2] = v.z; xs[r][c4 + 3] = v.w;
  }
  __syncthreads();
  int node = tid & 63, og = tid >> 6;
  int o = og * 4;
  float a0 = 0.f, a1 = 0.f, a2 = 0.f, a3 = 0.f;
  for (int k = 0; k < 128; ++k){
    float v = xs[node][k];
    a0 += v * wl[k * 16 + o + 0];
    a1 += v * wl[k * 16 + o + 1];
    a2 += v * wl[k * 16 + o + 2];
    a3 += v * wl[k * 16 + o + 3];
  }
  int n = n0 + node;
  if (n < N){
    if (o < 8){
      s[n * 8 + o + 0] = a0; s[n * 8 + o + 1] = a1;
      s[n * 8 + o + 2] = a2; s[n * 8 + o + 3] = a3;
    } else {
      int oo = o - 8;
      t[n * 8 + oo + 0] = a0; t[n * 8 + oo + 1] = a1;
      t[n * 8 + oo + 2] = a2; t[n * 8 + oo + 3] = a3;
    }
  }
  for (int i = tid; i < 4096; i += 256){
    int r = i >> 6, j = i & 63;
    int n2 = n0 + r;
    if (n2 < N)
      xb[(size_t)n2 * 64 + j] = f2bf(xs[r][2 * j]) | (f2bf(xs[r][2 * j + 1]) << 16);
  }
}

// ---------------- agg1x: wave per dst node; aggregate bf16 x per head -> y[N,8,128] ----
__global__ __launch_bounds__(256) void k_agg1x(
    const unsigned int* __restrict__ xb,   // [N][64] uint = [N][128] bf16
    const float* __restrict__ s, const float* __restrict__ t,
    const int* __restrict__ rowptr, const int* __restrict__ esrc,
    unsigned int* __restrict__ y, int N)   // [N][512] uint = [N][8][128] bf16
{
  __shared__ float lal[4][128];
  int wslot = threadIdx.x >> 6;
  int n = blockIdx.x * 4 + wslot;
  if (n >= N) return;
  int lane = threadIdx.x & 63;
  int row0 = rowptr[n], deg = rowptr[n + 1] - row0;
  int h = lane & 7;

  float tn = t[(size_t)n * 8 + h];
  float sn = s[(size_t)n * 8 + h];
  float selfe = __expf(leaky(sn + tn));

  // per-head denominator (head = lane&7), no max subtraction (logits bounded)
  float d = (lane < 8) ? selfe : 0.f;
  for (int e = lane >> 3; e < deg; e += 8){
    int src = esrc[row0 + e];
    d += __expf(leaky(s[(size_t)src * 8 + h] + tn));
  }
  d += __shfl_xor(d, 8, 64);
  d += __shfl_xor(d, 16, 64);
  d += __shfl_xor(d, 32, 64);
  float iden = 1.f / d;                  // every lane holds denom of its own head

  float acc[16];
  #pragma unroll
  for (int i = 0; i < 16; ++i) acc[i] = 0.f;

  // self message
  {
    float sf = selfe * iden;
    float a[8];
    #pragma unroll
    for (int hh = 0; hh < 8; ++hh) a[hh] = __shfl(sf, hh, 64);
    unsigned int v = xb[(size_t)n * 64 + lane];
    float f0 = __uint_as_float(v << 16);
    float f1 = __uint_as_float(v & 0xffff0000u);
    #pragma unroll
    for (int hh = 0; hh < 8; ++hh){
      acc[2 * hh]     += a[hh] * f0;
      acc[2 * hh + 1] += a[hh] * f1;
    }
  }

  float* lb = lal[wslot];
  for (int base = 0; base < deg; base += 8){
    float* la = lb + ((base >> 3) & 1) * 64;   // double-buffer (WAR safety)
    int e = base + (lane >> 3);
    int srcl = 0; float av = 0.f;
    if (e < deg){
      srcl = esrc[row0 + e];
      av = __expf(leaky(s[(size_t)srcl * 8 + h] + tn)) * iden;  // alpha[e][h]
    }
    la[lane] = av;
    int cnt = min(8, deg - base);
#define EDGE_BODY(j) { \
      float4 q0 = *(float4*)&la[(j) * 8]; \
      float4 q1 = *(float4*)&la[(j) * 8 + 4]; \
      int sj = __shfl(srcl, (j) << 3, 64); \
      unsigned int v = xb[(size_t)sj * 64 + lane]; \
      float f0 = __uint_as_float(v << 16); \
      float f1 = __uint_as_float(v & 0xffff0000u); \
      acc[0]  += q0.x * f0; acc[1]  += q0.x * f1; \
      acc[2]  += q0.y * f0; acc[3]  += q0.y * f1; \
      acc[4]  += q0.z * f0; acc[5]  += q0.z * f1; \
      acc[6]  += q0.w * f0; acc[7]  += q0.w * f1; \
      acc[8]  += q1.x * f0; acc[9]  += q1.x * f1; \
      acc[10] += q1.y * f0; acc[11] += q1.y * f1; \
      acc[12] += q1.z * f0; acc[13] += q1.z * f1; \
      acc[14] += q1.w * f0; acc[15] += q1.w * f1; }
    if (cnt == 8){
      #pragma unroll
      for (int j = 0; j < 8; ++j) EDGE_BODY(j)
    } else {
      for (int j = 0; j < cnt; ++j) EDGE_BODY(j)
    }
#undef EDGE_BODY
  }

  unsigned int* yr = y + (size_t)n * 512;
  #pragma unroll
  for (int hh = 0; hh < 8; ++hh)
    yr[hh * 64 + lane] = f2bf(acc[2 * hh]) | (f2bf(acc[2 * hh + 1]) << 16);
}

// ---------------- gemmy: out = y @ W1 (per head, MFMA, W1 hi+lo) ; fused relu+b1, .W2 ->
// xh2[n].  Block: 32 nodes, 4 waves; wave w handles heads 2w, 2w+1 for all 32 nodes.
__global__ __launch_bounds__(256) void k_gemmy(
    const short* __restrict__ y,          // bf16 [N][1024]
    const bf16x8* __restrict__ packh, const bf16x8* __restrict__ packl,
    const float* __restrict__ b1, const float* __restrict__ W2,
    float* __restrict__ xh2, int N)
{
  __shared__ float red[4][32];
  int tid = threadIdx.x;
  int w = tid >> 6, l = tid & 63;
  int m0 = blockIdx.x * 32;
  int lr = l & 15, lg = l >> 4;           // lr: A-row & D-col ; lg: k-group / D-row-group
  float pnode[8];
  #pragma unroll
  for (int i = 0; i < 8; ++i) pnode[i] = 0.f;

  bf16x8 az;
  #pragma unroll
  for (int i = 0; i < 8; ++i) az[i] = 0;

  #pragma unroll
  for (int hh = 0; hh < 2; ++hh){
    int h = 2 * w + hh;
    bf16x8 A[2][4];
    #pragma unroll
    for (int mt = 0; mt < 2; ++mt){
      int node = m0 + mt * 16 + lr;
      const short* ap = y + (size_t)node * 1024 + h * 128 + lg * 8;
      #pragma unroll
      for (int kt = 0; kt < 4; ++kt)
        A[mt][kt] = (node < N) ? *(const bf16x8*)(ap + kt * 32) : az;
    }
    #pragma unroll
    for (int ctl = 0; ctl < 4; ++ctl){
      int pb = ((h * 4 + ctl) * 4) * 64 + l;
      f32x4 acc0 = {0.f, 0.f, 0.f, 0.f}, acc1 = {0.f, 0.f, 0.f, 0.f};
      #pragma unroll
      for (int kt = 0; kt < 4; ++kt){
        bf16x8 bh = packh[pb + kt * 64];
        bf16x8 bl = packl[pb + kt * 64];
        acc0 = __builtin_amdgcn_mfma_f32_16x16x32_bf16(A[0][kt], bh, acc0, 0, 0, 0);
        acc0 = __builtin_amdgcn_mfma_f32_16x16x32_bf16(A[0][kt], bl, acc0, 0, 0, 0);
        acc1 = __builtin_amdgcn_mfma_f32_16x16x32_bf16(A[1][kt], bh, acc1, 0, 0, 0);
        acc1 = __builtin_amdgcn_mfma_f32_16x16x32_bf16(A[1][kt], bl, acc1, 0, 0, 0);
      }
      int gc = h * 64 + ctl * 16 + lr;
      float bb = b1[gc], wv = W2[gc];
      #pragma unroll
      for (int r = 0; r < 4; ++r){
        float o0 = acc0[r] + bb; o0 = o0 > 0.f ? o0 : 0.f;
        float o1 = acc1[r] + bb; o1 = o1 > 0.f ? o1 : 0.f;
        pnode[r]     += o0 * wv;          // node = m0 + lg*4 + r
        pnode[4 + r] += o1 * wv;          // node = m0 + 16 + lg*4 + r
      }
    }
  }
  #pragma unroll
  for (int r = 0; r < 8; ++r){
    float v = pnode[r];
    v += __shfl_xor(v, 1, 64);
    v += __shfl_xor(v, 2, 64);
    v += __shfl_xor(v, 4, 64);
    v += __shfl_xor(v, 8, 64);
    pnode[r] = v;
  }
  if (lr == 0){
    #pragma unroll
    for (int r = 0; r < 4; ++r){
      red[w][lg * 4 + r]      = pnode[r];
      red[w][16 + lg * 4 + r] = pnode[4 + r];
    }
  }
  __syncthreads();
  if (tid < 32){
    int node = m0 + tid;
    if (node < N)
      xh2[node] = red[0][tid] + red[1][tid] + red[2][tid] + red[3][tid];
  }
}

// ---------------- agg2: scalar GAT layer (H=1,C=1) ----------------
__global__ void k_agg2(const float* __restrict__ xh2, const int* __restrict__ rowptr,
                       const int* __restrict__ esrc,
                       const float* __restrict__ as2p, const float* __restrict__ ad2p,
                       const float* __restrict__ b2p,
                       float* __restrict__ out, int N)
{
  int n = blockIdx.x * blockDim.x + threadIdx.x;
  if (n >= N) return;
  float a_s = as2p[0], a_d = ad2p[0], b2 = b2p[0];
  float xn = xh2[n];
  float t2 = a_d * xn;
  float w0 = __expf(leaky(a_s * xn + t2));
  float den = w0, num = w0 * xn;
  int row1 = rowptr[n + 1];
  for (int e = rowptr[n]; e < row1; ++e){
    int src = esrc[e];
    float xs2 = xh2[src];
    float w = __expf(leaky(a_s * xs2 + t2));
    den += w; num += w * xs2;
  }
  out[n] = num / den + b2;
}

extern "C" void kernel_launch(void* const* d_in, const int* in_sizes, int n_in,
                              void* d_out, int out_size, void* d_ws, size_t ws_size,
                              hipStream_t stream) {
  const float* x   = (const float*)d_in[0];
  const int*   ei  = (const int*)d_in[1];
  const float* W1  = (const float*)d_in[2];
  const float* as1 = (const float*)d_in[3];
  const float* ad1 = (const float*)d_in[4];
  const float* b1  = (const float*)d_in[5];
  const float* W2  = (const float*)d_in[6];
  const float* as2 = (const float*)d_in[7];
  const float* ad2 = (const float*)d_in[8];
  const float* b2  = (const float*)d_in[9];
  float* out = (float*)d_out;

  int N = in_sizes[0] / 128;
  int E = in_sizes[1] / 2;
  const int* src_in = ei;
  const int* dst_in = ei + E;

  char* w = (char*)d_ws;
  auto alloc = [&](size_t bytes){ void* p = (void*)w; w += (bytes + 255) & ~(size_t)255; return p; };
  unsigned int* y    = (unsigned int*)alloc((size_t)N * 512 * 4);   // 102.4 MB
  unsigned int* xb   = (unsigned int*)alloc((size_t)N * 64 * 4);    // 12.8 MB
  float* s      = (float*)alloc((size_t)N * 8 * 4);
  float* t      = (float*)alloc((size_t)N * 8 * 4);
  float* xh2    = (float*)alloc((size_t)N * 4);
  int*   deg    = (int*)alloc((size_t)N * 4);
  int*   rowptr = (int*)alloc((size_t)(N + 1) * 4);
  int*   fill   = (int*)alloc((size_t)N * 4);
  int*   esrc   = (int*)alloc((size_t)E * 4);
  int*   tmp    = (int*)alloc((size_t)N * 4);
  int*   bsum   = (int*)alloc((size_t)1024 * 4);
  float* wst    = (float*)alloc((size_t)2048 * 4);
  bf16x8* packh = (bf16x8*)alloc((size_t)8192 * 16);
  bf16x8* packl = (bf16x8*)alloc((size_t)8192 * 16);

  int nb = (N + 255) / 256;

  hipMemsetAsync(deg, 0, (size_t)N * 4, stream);
  hipMemsetAsync(fill, 0, (size_t)N * 4, stream);
  k_hist<<<(E + 255) / 256, 256, 0, stream>>>(dst_in, E, deg);
  k_scan1<<<nb, 256, 0, stream>>>(deg, tmp, bsum, N);
  k_scan2<<<1, 256, 0, stream>>>(bsum, nb);
  k_scan3<<<nb, 256, 0, stream>>>(tmp, bsum, rowptr, N);
  k_fill<<<(E + 255) / 256, 256, 0, stream>>>(src_in, dst_in, E, rowptr, fill, esrc);
  k_wprep<<<33, 256, 0, stream>>>(W1, as1, ad1, wst, packh, packl);
  k_logits_xb<<<(N + 63) / 64, 256, 0, stream>>>(x, wst, s, t, xb, N);
  k_agg1x<<<(N + 3) / 4, 256, 0, stream>>>(xb, s, t, rowptr, esrc, y, N);
  k_gemmy<<<(N + 31) / 32, 256, 0, stream>>>((const short*)y, packh, packl, b1, W2, xh2, N);
  k_agg2<<<(N + 255) / 256, 256, 0, stream>>>(xh2, rowptr, esrc, as2, ad2, b2, out, N);
}

// Round 4
// 239.582 us; speedup vs baseline: 2.0792x; 1.0783x over previous
//
#include <hip/hip_runtime.h>
#include <math.h>

#define NEG_SLOPE 0.2f

typedef __attribute__((ext_vector_type(8))) short bf16x8;
typedef __attribute__((ext_vector_type(4))) float f32x4;

__device__ __forceinline__ float leaky(float v){ return v > 0.f ? v : NEG_SLOPE * v; }

// round-to-nearest-even f32 -> bf16 bits
static __device__ __forceinline__ unsigned int f2bf(float x){
  unsigned u = __float_as_uint(x);
  return (u + 0x7fffu + ((u >> 16) & 1u)) >> 16;
}

// ---------------- CSR build ----------------
__global__ void k_hist(const int* __restrict__ dst, int E, int* __restrict__ deg){
  int i = blockIdx.x * blockDim.x + threadIdx.x;
  if (i < E) atomicAdd(&deg[dst[i]], 1);
}

__global__ void k_scan1(const int* __restrict__ deg, int* __restrict__ tmp,
                        int* __restrict__ bsum, int N){
  __shared__ int ws[4];
  int tid = threadIdx.x;
  int i = blockIdx.x * 256 + tid;
  int v = (i < N) ? deg[i] : 0;
  int lane = tid & 63, wv = tid >> 6;
  int x = v;
  #pragma unroll
  for (int off = 1; off < 64; off <<= 1){
    int y = __shfl_up(x, off, 64);
    if (lane >= off) x += y;
  }
  if (lane == 63) ws[wv] = x;
  __syncthreads();
  int p = 0;
  for (int w = 0; w < wv; ++w) p += ws[w];
  x += p;
  if (i < N) tmp[i] = x;
  if (tid == 255) bsum[blockIdx.x] = x;
}

__global__ void k_scan2(int* __restrict__ bsum, int nb){
  __shared__ int ws[4];
  int tid = threadIdx.x;
  int v = (tid < nb) ? bsum[tid] : 0;
  int lane = tid & 63, wv = tid >> 6;
  int x = v;
  #pragma unroll
  for (int off = 1; off < 64; off <<= 1){
    int y = __shfl_up(x, off, 64);
    if (lane >= off) x += y;
  }
  if (lane == 63) ws[wv] = x;
  __syncthreads();
  int p = 0;
  for (int w = 0; w < wv; ++w) p += ws[w];
  x += p;
  if (tid < nb) bsum[tid] = x;
}

__global__ void k_scan3(const int* __restrict__ tmp, const int* __restrict__ bsum,
                        int* __restrict__ rowptr, int N){
  int i = blockIdx.x * 256 + threadIdx.x;
  if (i < N) rowptr[i + 1] = tmp[i] + (blockIdx.x ? bsum[blockIdx.x - 1] : 0);
  if (i == 0) rowptr[0] = 0;
}

__global__ void k_fill(const int* __restrict__ src, const int* __restrict__ dst, int E,
                       const int* __restrict__ rowptr, int* __restrict__ fill,
                       int* __restrict__ esrc){
  int i = blockIdx.x * blockDim.x + threadIdx.x;
  if (i < E){
    int d = dst[i];
    int pos = rowptr[d] + atomicAdd(&fill[d], 1);
    esrc[pos] = src[i];
  }
}

// ---------------- weight prep: wst logit-weights; W1 packed into B-fragments (bf16) ----
// pack entry g = ((h*4 + ctl)*4 + kt)*64 + lane ; reg i holds
//   W1[kt*32 + (lane>>4)*8 + i][h*64 + ctl*16 + (lane&15)]
__global__ void k_wprep(const float* __restrict__ W1, const float* __restrict__ as,
                        const float* __restrict__ ad, float* __restrict__ wst,
                        bf16x8* __restrict__ packh){
  int b = blockIdx.x, t = threadIdx.x;
  if (b == 0){
    int k = t & 127, half = t >> 7;
    const float* a = half ? ad : as;
    for (int h = 0; h < 8; ++h){
      float sum = 0.f;
      for (int c = 0; c < 64; ++c) sum += W1[(size_t)k * 512 + h * 64 + c] * a[h * 64 + c];
      wst[k * 16 + half * 8 + h] = sum;
    }
  } else {
    int g = (b - 1) * 256 + t;           // 0..8191
    int lane = g & 63, kt = (g >> 6) & 3, ctl = (g >> 8) & 3, h = g >> 10;
    int gc = h * 64 + ctl * 16 + (lane & 15);
    int k0 = kt * 32 + (lane >> 4) * 8;
    bf16x8 hv;
    #pragma unroll
    for (int i = 0; i < 8; ++i)
      hv[i] = (short)f2bf(W1[(size_t)(k0 + i) * 512 + gc]);
    packh[g] = hv;
  }
}

// ---------------- logits (fp32 exact) + xb = bf16(x) ----------------
__global__ __launch_bounds__(256) void k_logits_xb(const float* __restrict__ x,
                                                   const float* __restrict__ wst,
                                                   float* __restrict__ s, float* __restrict__ t,
                                                   unsigned int* __restrict__ xb, int N){
  __shared__ float xs[64][132];
  __shared__ float wl[2048];
  int tid = threadIdx.x;
  int n0 = blockIdx.x * 64;
  for (int i = tid; i < 2048; i += 256) wl[i] = wst[i];
  for (int i = tid; i < 2048; i += 256){
    int r = i >> 5, c4 = (i & 31) << 2;
    float4 v = make_float4(0.f, 0.f, 0.f, 0.f);
    if (n0 + r < N) v = *(const float4*)(x + (size_t)(n0 + r) * 128 + c4);
    xs[r][c4 + 0] = v.x; xs[r][c4 + 1] = v.y; xs[r][c4 + 2] = v.z; xs[r][c4 + 3] = v.w;
  }
  __syncthreads();
  int node = tid & 63, og = tid >> 6;
  int o = og * 4;
  float a0 = 0.f, a1 = 0.f, a2 = 0.f, a3 = 0.f;
  for (int k = 0; k < 128; ++k){
    float v = xs[node][k];
    a0 += v * wl[k * 16 + o + 0];
    a1 += v * wl[k * 16 + o + 1];
    a2 += v * wl[k * 16 + o + 2];
    a3 += v * wl[k * 16 + o + 3];
  }
  int n = n0 + node;
  if (n < N){
    if (o < 8){
      s[n * 8 + o + 0] = a0; s[n * 8 + o + 1] = a1;
      s[n * 8 + o + 2] = a2; s[n * 8 + o + 3] = a3;
    } else {
      int oo = o - 8;
      t[n * 8 + oo + 0] = a0; t[n * 8 + oo + 1] = a1;
      t[n * 8 + oo + 2] = a2; t[n * 8 + oo + 3] = a3;
    }
  }
  for (int i = tid; i < 4096; i += 256){
    int r = i >> 6, j = i & 63;
    int n2 = n0 + r;
    if (n2 < N)
      xb[(size_t)n2 * 64 + j] = f2bf(xs[r][2 * j]) | (f2bf(xs[r][2 * j + 1]) << 16);
  }
}

// ---------------- fused: per-node aggregation (into LDS) + MFMA projection + relu.W2 ----
// Block: 16 nodes, 4 waves. Phase 1: wave w aggregates nodes w*4..w*4+3 (one-pass,
// un-normalized softmax; 8-deep gather prefetch). bf16 y tile lives in LDS
// (XOR-swizzled: byte ^= (node&7)<<4 to kill the node-stride-2048 bank conflict).
// Phase 2: per wave heads 2w,2w+1: MFMA out = y @ W1h, fused relu(+b1).W2 -> xh2.
__global__ __launch_bounds__(256) void k_agg_gemm(
    const unsigned int* __restrict__ xb,   // [N][64] uint = [N][128] bf16
    const float* __restrict__ s, const float* __restrict__ t,
    const int* __restrict__ rowptr, const int* __restrict__ esrc,
    const bf16x8* __restrict__ packh,
    const float* __restrict__ b1, const float* __restrict__ W2,
    float* __restrict__ xh2, int N)
{
  __shared__ unsigned int ylds[8192];      // 16 nodes x 1024 bf16 = 32 KB
  __shared__ float lal[4][128];
  __shared__ float red[4][16];
  int tid = threadIdx.x;
  int w = tid >> 6, lane = tid & 63;
  int m0 = blockIdx.x * 16;
  int h = lane & 7;
  int es = lane >> 3;

  // ---------------- phase 1: aggregation ----------------
  for (int ni = 0; ni < 4; ++ni){
    int nl = w * 4 + ni;                   // local node 0..15
    int n = m0 + nl;
    float acc[16];
    #pragma unroll
    for (int i = 0; i < 16; ++i) acc[i] = 0.f;

    if (n < N){
      int row0 = rowptr[n], deg = rowptr[n + 1] - row0;
      float tn = t[(size_t)n * 8 + h];
      float sn = s[(size_t)n * 8 + h];
      float selfe = __expf(leaky(sn + tn));

      // self message (un-normalized)
      {
        unsigned int v = xb[(size_t)n * 64 + lane];
        float f0 = __uint_as_float(v << 16);
        float f1 = __uint_as_float(v & 0xffff0000u);
        #pragma unroll
        for (int hh = 0; hh < 8; ++hh){
          float a = __shfl(selfe, hh, 64);
          acc[2 * hh]     += a * f0;
          acc[2 * hh + 1] += a * f1;
        }
      }
      float dsum = (lane < 8) ? selfe : 0.f;

      float* lb = lal[w];
      for (int base = 0; base < deg; base += 8){
        float* la = lb + ((base >> 3) & 1) * 64;   // double-buffer (WAR)
        int e = base + es;
        int cnt = min(8, deg - base);
        int srcl = 0;
        if (e < deg) srcl = esrc[row0 + e];
        float sv = s[(size_t)srcl * 8 + h];        // gather (srcl=0 safe for OOB)
        // broadcast src ids, issue all 8 x-gathers up-front (MLP=8)
        int sj[8];
        #pragma unroll
        for (int j = 0; j < 8; ++j) sj[j] = __shfl(srcl, j << 3, 64);
        unsigned int vv[8];
        #pragma unroll
        for (int j = 0; j < 8; ++j) vv[j] = xb[(size_t)sj[j] * 64 + lane];
        // un-normalized numerator for (edge es, head h)
        float ev = (e < deg) ? __expf(leaky(sv + tn)) : 0.f;
        dsum += ev;
        la[lane] = ev;
        #pragma unroll
        for (int j = 0; j < 8; ++j){
          if (j < cnt){
            float4 q0 = *(float4*)&la[j * 8];
            float4 q1 = *(float4*)&la[j * 8 + 4];
            float f0 = __uint_as_float(vv[j] << 16);
            float f1 = __uint_as_float(vv[j] & 0xffff0000u);
            acc[0]  += q0.x * f0; acc[1]  += q0.x * f1;
            acc[2]  += q0.y * f0; acc[3]  += q0.y * f1;
            acc[4]  += q0.z * f0; acc[5]  += q0.z * f1;
            acc[6]  += q0.w * f0; acc[7]  += q0.w * f1;
            acc[8]  += q1.x * f0; acc[9]  += q1.x * f1;
            acc[10] += q1.y * f0; acc[11] += q1.y * f1;
            acc[12] += q1.z * f0; acc[13] += q1.z * f1;
            acc[14] += q1.w * f0; acc[15] += q1.w * f1;
          }
        }
      }

      // finalize: per-head denominators, normalize
      dsum += __shfl_xor(dsum, 8, 64);
      dsum += __shfl_xor(dsum, 16, 64);
      dsum += __shfl_xor(dsum, 32, 64);
      float iden = 1.f / dsum;             // lane's own head h
      #pragma unroll
      for (int hh = 0; hh < 8; ++hh){
        float a = __shfl(iden, hh, 64);
        acc[2 * hh]     *= a;
        acc[2 * hh + 1] *= a;
      }
    }

    // write y tile to LDS (swizzled); zeros for n >= N
    #pragma unroll
    for (int hh = 0; hh < 8; ++hh){
      unsigned int p = f2bf(acc[2 * hh]) | (f2bf(acc[2 * hh + 1]) << 16);
      unsigned int byte = (unsigned)(nl * 2048 + hh * 256 + lane * 4);
      byte ^= (unsigned)((nl & 7) << 4);
      ylds[byte >> 2] = p;
    }
  }
  __syncthreads();

  // ---------------- phase 2: MFMA projection + fused epilogue ----------------
  int lr = lane & 15, lg = lane >> 4;
  float pnode[4] = {0.f, 0.f, 0.f, 0.f};
  #pragma unroll
  for (int hh = 0; hh < 2; ++hh){
    int hD = 2 * w + hh;
    bf16x8 A[4];
    #pragma unroll
    for (int kt = 0; kt < 4; ++kt){
      unsigned int byte = (unsigned)(lr * 2048 + hD * 256 + kt * 64 + lg * 16);
      byte ^= (unsigned)((lr & 7) << 4);
      A[kt] = *(const bf16x8*)((const char*)ylds + byte);
    }
    #pragma unroll
    for (int ctl = 0; ctl < 4; ++ctl){
      f32x4 acc2 = {0.f, 0.f, 0.f, 0.f};
      int pb = ((hD * 4 + ctl) * 4) * 64 + lane;
      #pragma unroll
      for (int kt = 0; kt < 4; ++kt)
        acc2 = __builtin_amdgcn_mfma_f32_16x16x32_bf16(A[kt], packh[pb + kt * 64], acc2, 0, 0, 0);
      int gc = hD * 64 + ctl * 16 + lr;
      float bb = b1[gc], wv = W2[gc];
      #pragma unroll
      for (int r = 0; r < 4; ++r){
        float o = acc2[r] + bb; o = o > 0.f ? o : 0.f;
        pnode[r] += o * wv;                // node = m0 + lg*4 + r
      }
    }
  }
  #pragma unroll
  for (int r = 0; r < 4; ++r){
    float v = pnode[r];
    v += __shfl_xor(v, 1, 64);
    v += __shfl_xor(v, 2, 64);
    v += __shfl_xor(v, 4, 64);
    v += __shfl_xor(v, 8, 64);
    pnode[r] = v;
  }
  if (lr == 0){
    #pragma unroll
    for (int r = 0; r < 4; ++r) red[w][lg * 4 + r] = pnode[r];
  }
  __syncthreads();
  if (tid < 16){
    int node = m0 + tid;
    if (node < N)
      xh2[node] = red[0][tid] + red[1][tid] + red[2][tid] + red[3][tid];
  }
}

// ---------------- agg2: scalar GAT layer (H=1,C=1) ----------------
__global__ void k_agg2(const float* __restrict__ xh2, const int* __restrict__ rowptr,
                       const int* __restrict__ esrc,
                       const float* __restrict__ as2p, const float* __restrict__ ad2p,
                       const float* __restrict__ b2p,
                       float* __restrict__ out, int N)
{
  int n = blockIdx.x * blockDim.x + threadIdx.x;
  if (n >= N) return;
  float a_s = as2p[0], a_d = ad2p[0], b2 = b2p[0];
  float xn = xh2[n];
  float t2 = a_d * xn;
  float w0 = __expf(leaky(a_s * xn + t2));
  float den = w0, num = w0 * xn;
  int row1 = rowptr[n + 1];
  for (int e = rowptr[n]; e < row1; ++e){
    int src = esrc[e];
    float xs2 = xh2[src];
    float w = __expf(leaky(a_s * xs2 + t2));
    den += w; num += w * xs2;
  }
  out[n] = num / den + b2;
}

extern "C" void kernel_launch(void* const* d_in, const int* in_sizes, int n_in,
                              void* d_out, int out_size, void* d_ws, size_t ws_size,
                              hipStream_t stream) {
  const float* x   = (const float*)d_in[0];
  const int*   ei  = (const int*)d_in[1];
  const float* W1  = (const float*)d_in[2];
  const float* as1 = (const float*)d_in[3];
  const float* ad1 = (const float*)d_in[4];
  const float* b1  = (const float*)d_in[5];
  const float* W2  = (const float*)d_in[6];
  const float* as2 = (const float*)d_in[7];
  const float* ad2 = (const float*)d_in[8];
  const float* b2  = (const float*)d_in[9];
  float* out = (float*)d_out;

  int N = in_sizes[0] / 128;
  int E = in_sizes[1] / 2;
  const int* src_in = ei;
  const int* dst_in = ei + E;

  char* w = (char*)d_ws;
  auto alloc = [&](size_t bytes){ void* p = (void*)w; w += (bytes + 255) & ~(size_t)255; return p; };
  unsigned int* xb   = (unsigned int*)alloc((size_t)N * 64 * 4);    // 12.8 MB
  float* s      = (float*)alloc((size_t)N * 8 * 4);
  float* t      = (float*)alloc((size_t)N * 8 * 4);
  float* xh2    = (float*)alloc((size_t)N * 4);
  int*   cnts   = (int*)alloc((size_t)2 * N * 4);                   // deg | fill
  int*   deg    = cnts;
  int*   fill   = cnts + N;
  int*   rowptr = (int*)alloc((size_t)(N + 1) * 4);
  int*   esrc   = (int*)alloc((size_t)E * 4);
  int*   tmp    = (int*)alloc((size_t)N * 4);
  int*   bsum   = (int*)alloc((size_t)1024 * 4);
  float* wst    = (float*)alloc((size_t)2048 * 4);
  bf16x8* packh = (bf16x8*)alloc((size_t)8192 * 16);

  int nb = (N + 255) / 256;

  hipMemsetAsync(cnts, 0, (size_t)2 * N * 4, stream);
  k_hist<<<(E + 255) / 256, 256, 0, stream>>>(dst_in, E, deg);
  k_scan1<<<nb, 256, 0, stream>>>(deg, tmp, bsum, N);
  k_scan2<<<1, 256, 0, stream>>>(bsum, nb);
  k_scan3<<<nb, 256, 0, stream>>>(tmp, bsum, rowptr, N);
  k_fill<<<(E + 255) / 256, 256, 0, stream>>>(src_in, dst_in, E, rowptr, fill, esrc);
  k_wprep<<<33, 256, 0, stream>>>(W1, as1, ad1, wst, packh);
  k_logits_xb<<<(N + 63) / 64, 256, 0, stream>>>(x, wst, s, t, xb, N);
  k_agg_gemm<<<(N + 15) / 16, 256, 0, stream>>>(xb, s, t, rowptr, esrc, packh, b1, W2, xh2, N);
  k_agg2<<<(N + 255) / 256, 256, 0, stream>>>(xh2, rowptr, esrc, as2, ad2, b2, out, N);
}

// Round 5
// 238.443 us; speedup vs baseline: 2.0891x; 1.0048x over previous
//
#include <hip/hip_runtime.h>
#include <math.h>

#define NEG_SLOPE 0.2f

typedef __attribute__((ext_vector_type(8))) short bf16x8;
typedef __attribute__((ext_vector_type(4))) float f32x4;

__device__ __forceinline__ float leaky(float v){ return v > 0.f ? v : NEG_SLOPE * v; }

// round-to-nearest-even f32 -> bf16 bits
static __device__ __forceinline__ unsigned int f2bf(float x){
  unsigned u = __float_as_uint(x);
  return (u + 0x7fffu + ((u >> 16) & 1u)) >> 16;
}

// ---------------- CSR build ----------------
__global__ void k_hist(const int* __restrict__ dst, int E, int* __restrict__ deg){
  int i = blockIdx.x * blockDim.x + threadIdx.x;
  if (i < E) atomicAdd(&deg[dst[i]], 1);
}

__global__ void k_scan1(const int* __restrict__ deg, int* __restrict__ tmp,
                        int* __restrict__ bsum, int N){
  __shared__ int ws[4];
  int tid = threadIdx.x;
  int i = blockIdx.x * 256 + tid;
  int v = (i < N) ? deg[i] : 0;
  int lane = tid & 63, wv = tid >> 6;
  int x = v;
  #pragma unroll
  for (int off = 1; off < 64; off <<= 1){
    int y = __shfl_up(x, off, 64);
    if (lane >= off) x += y;
  }
  if (lane == 63) ws[wv] = x;
  __syncthreads();
  int p = 0;
  for (int w = 0; w < wv; ++w) p += ws[w];
  x += p;
  if (i < N) tmp[i] = x;
  if (tid == 255) bsum[blockIdx.x] = x;
}

__global__ void k_scan2(int* __restrict__ bsum, int nb){
  __shared__ int ws[4];
  int tid = threadIdx.x;
  int v = (tid < nb) ? bsum[tid] : 0;
  int lane = tid & 63, wv = tid >> 6;
  int x = v;
  #pragma unroll
  for (int off = 1; off < 64; off <<= 1){
    int y = __shfl_up(x, off, 64);
    if (lane >= off) x += y;
  }
  if (lane == 63) ws[wv] = x;
  __syncthreads();
  int p = 0;
  for (int w = 0; w < wv; ++w) p += ws[w];
  x += p;
  if (tid < nb) bsum[tid] = x;
}

__global__ void k_scan3(const int* __restrict__ tmp, const int* __restrict__ bsum,
                        int* __restrict__ rowptr, int N){
  int i = blockIdx.x * 256 + threadIdx.x;
  if (i < N) rowptr[i + 1] = tmp[i] + (blockIdx.x ? bsum[blockIdx.x - 1] : 0);
  if (i == 0) rowptr[0] = 0;
}

__global__ void k_fill(const int* __restrict__ src, const int* __restrict__ dst, int E,
                       const int* __restrict__ rowptr, int* __restrict__ fill,
                       int* __restrict__ esrc){
  int i = blockIdx.x * blockDim.x + threadIdx.x;
  if (i < E){
    int d = dst[i];
    int pos = rowptr[d] + atomicAdd(&fill[d], 1);
    esrc[pos] = src[i];
  }
}

// ---------------- weight prep: wst logit-weights; W1 packed into B-fragments (bf16) ----
__global__ void k_wprep(const float* __restrict__ W1, const float* __restrict__ as,
                        const float* __restrict__ ad, float* __restrict__ wst,
                        bf16x8* __restrict__ packh){
  int b = blockIdx.x, t = threadIdx.x;
  if (b == 0){
    int k = t & 127, half = t >> 7;
    const float* a = half ? ad : as;
    for (int h = 0; h < 8; ++h){
      float sum = 0.f;
      for (int c = 0; c < 64; ++c) sum += W1[(size_t)k * 512 + h * 64 + c] * a[h * 64 + c];
      wst[k * 16 + half * 8 + h] = sum;
    }
  } else {
    int g = (b - 1) * 256 + t;           // 0..8191
    int lane = g & 63, kt = (g >> 6) & 3, ctl = (g >> 8) & 3, h = g >> 10;
    int gc = h * 64 + ctl * 16 + (lane & 15);
    int k0 = kt * 32 + (lane >> 4) * 8;
    bf16x8 hv;
    #pragma unroll
    for (int i = 0; i < 8; ++i)
      hv[i] = (short)f2bf(W1[(size_t)(k0 + i) * 512 + gc]);
    packh[g] = hv;
  }
}

// ---------------- logits (fp32 exact) + xb = bf16(x) ----------------
__global__ __launch_bounds__(256) void k_logits_xb(const float* __restrict__ x,
                                                   const float* __restrict__ wst,
                                                   float* __restrict__ s, float* __restrict__ t,
                                                   unsigned int* __restrict__ xb, int N){
  __shared__ float xs[64][132];
  __shared__ float wl[2048];
  int tid = threadIdx.x;
  int n0 = blockIdx.x * 64;
  for (int i = tid; i < 2048; i += 256) wl[i] = wst[i];
  for (int i = tid; i < 2048; i += 256){
    int r = i >> 5, c4 = (i & 31) << 2;
    float4 v = make_float4(0.f, 0.f, 0.f, 0.f);
    if (n0 + r < N) v = *(const float4*)(x + (size_t)(n0 + r) * 128 + c4);
    xs[r][c4 + 0] = v.x; xs[r][c4 + 1] = v.y; xs[r][c4 + 2] = v.z; xs[r][c4 + 3] = v.w;
  }
  __syncthreads();
  int node = tid & 63, og = tid >> 6;
  int o = og * 4;
  float a0 = 0.f, a1 = 0.f, a2 = 0.f, a3 = 0.f;
  for (int k = 0; k < 128; ++k){
    float v = xs[node][k];
    a0 += v * wl[k * 16 + o + 0];
    a1 += v * wl[k * 16 + o + 1];
    a2 += v * wl[k * 16 + o + 2];
    a3 += v * wl[k * 16 + o + 3];
  }
  int n = n0 + node;
  if (n < N){
    if (o < 8){
      s[n * 8 + o + 0] = a0; s[n * 8 + o + 1] = a1;
      s[n * 8 + o + 2] = a2; s[n * 8 + o + 3] = a3;
    } else {
      int oo = o - 8;
      t[n * 8 + oo + 0] = a0; t[n * 8 + oo + 1] = a1;
      t[n * 8 + oo + 2] = a2; t[n * 8 + oo + 3] = a3;
    }
  }
  for (int i = tid; i < 4096; i += 256){
    int r = i >> 6, j = i & 63;
    int n2 = n0 + r;
    if (n2 < N)
      xb[(size_t)n2 * 64 + j] = f2bf(xs[r][2 * j]) | (f2bf(xs[r][2 * j + 1]) << 16);
  }
}

// ---------------- fused aggregation + MFMA projection ----------------
// Phase 1 (per wave, 4 nodes): wide gathers — one dwordx4 per 4 edges (16 lanes/row),
// shfl-routed to channel owners; software-pipelined 2 chunks deep. Un-normalized
// one-pass softmax. y tile -> LDS (swizzled). Phase 2: per-wave heads 2w,2w+1 MFMA.
struct Chunk { int srcl; float sv; uint4 v0, v1; };

__global__ __launch_bounds__(256, 4) void k_agg_gemm(
    const unsigned int* __restrict__ xb,   // [N][64] uint = [N][128] bf16
    const float* __restrict__ s, const float* __restrict__ t,
    const int* __restrict__ rowptr, const int* __restrict__ esrc,
    const bf16x8* __restrict__ packh,
    const float* __restrict__ b1, const float* __restrict__ W2,
    float* __restrict__ xh2, int N)
{
  __shared__ unsigned int ylds[8192];      // 16 nodes x 1024 bf16 = 32 KB
  __shared__ float lal[4][128];
  __shared__ float red[4][16];
  const uint4* xb4 = (const uint4*)xb;
  int tid = threadIdx.x;
  int w = tid >> 6, lane = tid & 63;
  int m0 = blockIdx.x * 16;
  int h = lane & 7;
  int es = lane >> 3;
  int j0 = lane >> 4;                      // my edge slot within a gather inst
  int q4 = lane & 15;                      // my 16B slot within an edge row
  int rl = lane >> 2;                      // row-lane base for routing shfl

  // ---------------- phase 1 ----------------
  for (int ni = 0; ni < 4; ++ni){
    int nl = w * 4 + ni;
    int n = m0 + nl;
    float acc[16];
    #pragma unroll
    for (int i = 0; i < 16; ++i) acc[i] = 0.f;

    if (n < N){
      int row0 = rowptr[n], deg = rowptr[n + 1] - row0;
      float tn = t[(size_t)n * 8 + h];
      float sn = s[(size_t)n * 8 + h];
      float selfe = __expf(leaky(sn + tn));

      // self message (un-normalized)
      {
        unsigned int v = xb[(size_t)n * 64 + lane];
        float f0 = __uint_as_float(v << 16);
        float f1 = __uint_as_float(v & 0xffff0000u);
        #pragma unroll
        for (int hh = 0; hh < 8; ++hh){
          float a = __shfl(selfe, hh, 64);
          acc[2 * hh]     += a * f0;
          acc[2 * hh + 1] += a * f1;
        }
      }
      float dsum = (lane < 8) ? selfe : 0.f;
      float* lb = lal[w];
      int nch = (deg + 7) >> 3;

      Chunk cur, nxt;
      // prefetch chunk 0
      if (nch > 0){
        int e = es;
        int srcl = (e < deg) ? esrc[row0 + e] : 0;
        cur.srcl = srcl;
        cur.sv = s[(size_t)srcl * 8 + h];
        int sA = __shfl(srcl, j0 << 3, 64);
        int sB = __shfl(srcl, (4 + j0) << 3, 64);
        cur.v0 = xb4[(size_t)sA * 16 + q4];
        cur.v1 = xb4[(size_t)sB * 16 + q4];
      }
      for (int c = 0; c < nch; ++c){
        if (c + 1 < nch){
          int e = (c + 1) * 8 + es;
          int srcl = (e < deg) ? esrc[row0 + e] : 0;
          nxt.srcl = srcl;
          nxt.sv = s[(size_t)srcl * 8 + h];
          int sA = __shfl(srcl, j0 << 3, 64);
          int sB = __shfl(srcl, (4 + j0) << 3, 64);
          nxt.v0 = xb4[(size_t)sA * 16 + q4];
          nxt.v1 = xb4[(size_t)sB * 16 + q4];
        }
        // alphas for chunk c
        int e = c * 8 + es;
        float ev = (e < deg) ? __expf(leaky(cur.sv + tn)) : 0.f;
        dsum += ev;
        float* lab = lb + ((c & 1) << 6);
        lab[lane] = ev;
        // consume 8 edges (4 from v0, 4 from v1)
        #pragma unroll
        for (int j = 0; j < 4; ++j){
          int sl = (j << 4) | rl;
          unsigned s0 = __shfl(cur.v0.x, sl, 64);
          unsigned s1 = __shfl(cur.v0.y, sl, 64);
          unsigned s2 = __shfl(cur.v0.z, sl, 64);
          unsigned s3 = __shfl(cur.v0.w, sl, 64);
          unsigned t01 = (lane & 1) ? s1 : s0;
          unsigned t23 = (lane & 1) ? s3 : s2;
          unsigned u   = (lane & 2) ? t23 : t01;
          float f0 = __uint_as_float(u << 16);
          float f1 = __uint_as_float(u & 0xffff0000u);
          float4 a0 = *(float4*)&lab[j * 8];
          float4 a1 = *(float4*)&lab[j * 8 + 4];
          acc[0]  += a0.x * f0; acc[1]  += a0.x * f1;
          acc[2]  += a0.y * f0; acc[3]  += a0.y * f1;
          acc[4]  += a0.z * f0; acc[5]  += a0.z * f1;
          acc[6]  += a0.w * f0; acc[7]  += a0.w * f1;
          acc[8]  += a1.x * f0; acc[9]  += a1.x * f1;
          acc[10] += a1.y * f0; acc[11] += a1.y * f1;
          acc[12] += a1.z * f0; acc[13] += a1.z * f1;
          acc[14] += a1.w * f0; acc[15] += a1.w * f1;
        }
        #pragma unroll
        for (int j = 0; j < 4; ++j){
          int sl = (j << 4) | rl;
          unsigned s0 = __shfl(cur.v1.x, sl, 64);
          unsigned s1 = __shfl(cur.v1.y, sl, 64);
          unsigned s2 = __shfl(cur.v1.z, sl, 64);
          unsigned s3 = __shfl(cur.v1.w, sl, 64);
          unsigned t01 = (lane & 1) ? s1 : s0;
          unsigned t23 = (lane & 1) ? s3 : s2;
          unsigned u   = (lane & 2) ? t23 : t01;
          float f0 = __uint_as_float(u << 16);
          float f1 = __uint_as_float(u & 0xffff0000u);
          float4 a0 = *(float4*)&lab[32 + j * 8];
          float4 a1 = *(float4*)&lab[32 + j * 8 + 4];
          acc[0]  += a0.x * f0; acc[1]  += a0.x * f1;
          acc[2]  += a0.y * f0; acc[3]  += a0.y * f1;
          acc[4]  += a0.z * f0; acc[5]  += a0.z * f1;
          acc[6]  += a0.w * f0; acc[7]  += a0.w * f1;
          acc[8]  += a1.x * f0; acc[9]  += a1.x * f1;
          acc[10] += a1.y * f0; acc[11] += a1.y * f1;
          acc[12] += a1.z * f0; acc[13] += a1.z * f1;
          acc[14] += a1.w * f0; acc[15] += a1.w * f1;
        }
        cur = nxt;
      }

      // finalize: per-head denominators, normalize
      dsum += __shfl_xor(dsum, 8, 64);
      dsum += __shfl_xor(dsum, 16, 64);
      dsum += __shfl_xor(dsum, 32, 64);
      float iden = 1.f / dsum;
      #pragma unroll
      for (int hh = 0; hh < 8; ++hh){
        float a = __shfl(iden, hh, 64);
        acc[2 * hh]     *= a;
        acc[2 * hh + 1] *= a;
      }
    }

    // write y tile to LDS (swizzled); zeros for n >= N
    #pragma unroll
    for (int hh = 0; hh < 8; ++hh){
      unsigned int p = f2bf(acc[2 * hh]) | (f2bf(acc[2 * hh + 1]) << 16);
      unsigned int byte = (unsigned)(nl * 2048 + hh * 256 + lane * 4);
      byte ^= (unsigned)((nl & 7) << 4);
      ylds[byte >> 2] = p;
    }
  }
  __syncthreads();

  // ---------------- phase 2: MFMA projection + fused epilogue ----------------
  int lr = lane & 15, lg = lane >> 4;
  float pnode[4] = {0.f, 0.f, 0.f, 0.f};
  #pragma unroll
  for (int hh = 0; hh < 2; ++hh){
    int hD = 2 * w + hh;
    bf16x8 A[4];
    #pragma unroll
    for (int kt = 0; kt < 4; ++kt){
      unsigned int byte = (unsigned)(lr * 2048 + hD * 256 + kt * 64 + lg * 16);
      byte ^= (unsigned)((lr & 7) << 4);
      A[kt] = *(const bf16x8*)((const char*)ylds + byte);
    }
    #pragma unroll
    for (int ctl = 0; ctl < 4; ++ctl){
      f32x4 acc2 = {0.f, 0.f, 0.f, 0.f};
      int pb = ((hD * 4 + ctl) * 4) * 64 + lane;
      #pragma unroll
      for (int kt = 0; kt < 4; ++kt)
        acc2 = __builtin_amdgcn_mfma_f32_16x16x32_bf16(A[kt], packh[pb + kt * 64], acc2, 0, 0, 0);
      int gc = hD * 64 + ctl * 16 + lr;
      float bb = b1[gc], wv = W2[gc];
      #pragma unroll
      for (int r = 0; r < 4; ++r){
        float o = acc2[r] + bb; o = o > 0.f ? o : 0.f;
        pnode[r] += o * wv;                // node = m0 + lg*4 + r
      }
    }
  }
  #pragma unroll
  for (int r = 0; r < 4; ++r){
    float v = pnode[r];
    v += __shfl_xor(v, 1, 64);
    v += __shfl_xor(v, 2, 64);
    v += __shfl_xor(v, 4, 64);
    v += __shfl_xor(v, 8, 64);
    pnode[r] = v;
  }
  if (lr == 0){
    #pragma unroll
    for (int r = 0; r < 4; ++r) red[w][lg * 4 + r] = pnode[r];
  }
  __syncthreads();
  if (tid < 16){
    int node = m0 + tid;
    if (node < N)
      xh2[node] = red[0][tid] + red[1][tid] + red[2][tid] + red[3][tid];
  }
}

// ---------------- agg2: scalar GAT layer (H=1,C=1) ----------------
__global__ void k_agg2(const float* __restrict__ xh2, const int* __restrict__ rowptr,
                       const int* __restrict__ esrc,
                       const float* __restrict__ as2p, const float* __restrict__ ad2p,
                       const float* __restrict__ b2p,
                       float* __restrict__ out, int N)
{
  int n = blockIdx.x * blockDim.x + threadIdx.x;
  if (n >= N) return;
  float a_s = as2p[0], a_d = ad2p[0], b2 = b2p[0];
  float xn = xh2[n];
  float t2 = a_d * xn;
  float w0 = __expf(leaky(a_s * xn + t2));
  float den = w0, num = w0 * xn;
  int row1 = rowptr[n + 1];
  for (int e = rowptr[n]; e < row1; ++e){
    int src = esrc[e];
    float xs2 = xh2[src];
    float w = __expf(leaky(a_s * xs2 + t2));
    den += w; num += w * xs2;
  }
  out[n] = num / den + b2;
}

extern "C" void kernel_launch(void* const* d_in, const int* in_sizes, int n_in,
                              void* d_out, int out_size, void* d_ws, size_t ws_size,
                              hipStream_t stream) {
  const float* x   = (const float*)d_in[0];
  const int*   ei  = (const int*)d_in[1];
  const float* W1  = (const float*)d_in[2];
  const float* as1 = (const float*)d_in[3];
  const float* ad1 = (const float*)d_in[4];
  const float* b1  = (const float*)d_in[5];
  const float* W2  = (const float*)d_in[6];
  const float* as2 = (const float*)d_in[7];
  const float* ad2 = (const float*)d_in[8];
  const float* b2  = (const float*)d_in[9];
  float* out = (float*)d_out;

  int N = in_sizes[0] / 128;
  int E = in_sizes[1] / 2;
  const int* src_in = ei;
  const int* dst_in = ei + E;

  char* w = (char*)d_ws;
  auto alloc = [&](size_t bytes){ void* p = (void*)w; w += (bytes + 255) & ~(size_t)255; return p; };
  unsigned int* xb   = (unsigned int*)alloc((size_t)N * 64 * 4);    // 12.8 MB
  float* s      = (float*)alloc((size_t)N * 8 * 4);
  float* t      = (float*)alloc((size_t)N * 8 * 4);
  float* xh2    = (float*)alloc((size_t)N * 4);
  int*   cnts   = (int*)alloc((size_t)2 * N * 4);                   // deg | fill
  int*   deg    = cnts;
  int*   fill   = cnts + N;
  int*   rowptr = (int*)alloc((size_t)(N + 1) * 4);
  int*   esrc   = (int*)alloc((size_t)E * 4);
  int*   tmp    = (int*)alloc((size_t)N * 4);
  int*   bsum   = (int*)alloc((size_t)1024 * 4);
  float* wst    = (float*)alloc((size_t)2048 * 4);
  bf16x8* packh = (bf16x8*)alloc((size_t)8192 * 16);

  int nb = (N + 255) / 256;

  hipMemsetAsync(cnts, 0, (size_t)2 * N * 4, stream);
  k_hist<<<(E + 255) / 256, 256, 0, stream>>>(dst_in, E, deg);
  k_scan1<<<nb, 256, 0, stream>>>(deg, tmp, bsum, N);
  k_scan2<<<1, 256, 0, stream>>>(bsum, nb);
  k_scan3<<<nb, 256, 0, stream>>>(tmp, bsum, rowptr, N);
  k_fill<<<(E + 255) / 256, 256, 0, stream>>>(src_in, dst_in, E, rowptr, fill, esrc);
  k_wprep<<<33, 256, 0, stream>>>(W1, as1, ad1, wst, packh);
  k_logits_xb<<<(N + 63) / 64, 256, 0, stream>>>(x, wst, s, t, xb, N);
  k_agg_gemm<<<(N + 15) / 16, 256, 0, stream>>>(xb, s, t, rowptr, esrc, packh, b1, W2, xh2, N);
  k_agg2<<<(N + 255) / 256, 256, 0, stream>>>(xh2, rowptr, esrc, as2, ad2, b2, out, N);
}

// Round 6
// 199.554 us; speedup vs baseline: 2.4963x; 1.1949x over previous
//
#include <hip/hip_runtime.h>
#include <math.h>

#define NEG_SLOPE 0.2f

typedef __attribute__((ext_vector_type(8))) short bf16x8;
typedef __attribute__((ext_vector_type(4))) float f32x4;

__device__ __forceinline__ float leaky(float v){ return v > 0.f ? v : NEG_SLOPE * v; }

// round-to-nearest-even f32 -> bf16 bits
static __device__ __forceinline__ unsigned int f2bf(float x){
  unsigned u = __float_as_uint(x);
  return (u + 0x7fffu + ((u >> 16) & 1u)) >> 16;
}

// ---------------- prep0: wst + packh (blocks 0..32) | hist (blocks 33..) ----------------
__global__ void k_prep0(const float* __restrict__ W1, const float* __restrict__ as,
                        const float* __restrict__ ad, float* __restrict__ wst,
                        bf16x8* __restrict__ packh,
                        const int* __restrict__ dst, int E, int* __restrict__ deg){
  int b = blockIdx.x, t = threadIdx.x;
  if (b == 0){
    int k = t & 127, half = t >> 7;
    const float* a = half ? ad : as;
    for (int h = 0; h < 8; ++h){
      float sum = 0.f;
      for (int c = 0; c < 64; ++c) sum += W1[(size_t)k * 512 + h * 64 + c] * a[h * 64 + c];
      wst[k * 16 + half * 8 + h] = sum;
    }
  } else if (b < 33){
    int g = (b - 1) * 256 + t;           // 0..8191
    int lane = g & 63, kt = (g >> 6) & 3, ctl = (g >> 8) & 3, h = g >> 10;
    int gc = h * 64 + ctl * 16 + (lane & 15);
    int k0 = kt * 32 + (lane >> 4) * 8;
    bf16x8 hv;
    #pragma unroll
    for (int i = 0; i < 8; ++i)
      hv[i] = (short)f2bf(W1[(size_t)(k0 + i) * 512 + gc]);
    packh[g] = hv;
  } else {
    int i = (b - 33) * 256 + t;
    if (i < E) atomicAdd(&deg[dst[i]], 1);
  }
}

// ---------------- hierarchical scan ----------------
__global__ void k_scan1(const int* __restrict__ deg, int* __restrict__ tmp,
                        int* __restrict__ bsum, int N){
  __shared__ int ws[4];
  int tid = threadIdx.x;
  int i = blockIdx.x * 256 + tid;
  int v = (i < N) ? deg[i] : 0;
  int lane = tid & 63, wv = tid >> 6;
  int x = v;
  #pragma unroll
  for (int off = 1; off < 64; off <<= 1){
    int y = __shfl_up(x, off, 64);
    if (lane >= off) x += y;
  }
  if (lane == 63) ws[wv] = x;
  __syncthreads();
  int p = 0;
  for (int w = 0; w < wv; ++w) p += ws[w];
  x += p;
  if (i < N) tmp[i] = x;
  if (tid == 255) bsum[blockIdx.x] = x;
}

__global__ void k_scan2(int* __restrict__ bsum, int nb){
  __shared__ int ws[4];
  int tid = threadIdx.x;
  int v = (tid < nb) ? bsum[tid] : 0;
  int lane = tid & 63, wv = tid >> 6;
  int x = v;
  #pragma unroll
  for (int off = 1; off < 64; off <<= 1){
    int y = __shfl_up(x, off, 64);
    if (lane >= off) x += y;
  }
  if (lane == 63) ws[wv] = x;
  __syncthreads();
  int p = 0;
  for (int w = 0; w < wv; ++w) p += ws[w];
  x += p;
  if (tid < nb) bsum[tid] = x;
}

// ---------------- fill3: rowptr materialization + CSR scatter (no scan3 kernel) ----------
__device__ __forceinline__ int rp_of(int j, const int* __restrict__ tmp,
                                     const int* __restrict__ bsum){
  if (j == 0) return 0;
  int i = j - 1, blk = i >> 8;
  return tmp[i] + (blk ? bsum[blk - 1] : 0);
}

__global__ void k_fill3(const int* __restrict__ src, const int* __restrict__ dst, int E,
                        const int* __restrict__ tmp, const int* __restrict__ bsum,
                        int* __restrict__ rowptr, int* __restrict__ fill,
                        int* __restrict__ esrc, int N){
  int i = blockIdx.x * blockDim.x + threadIdx.x;
  if (i <= N) rowptr[i] = rp_of(i, tmp, bsum);
  if (i < E){
    int d = dst[i];
    int row0 = rp_of(d, tmp, bsum);
    int pos = row0 + atomicAdd(&fill[d], 1);
    esrc[pos] = src[i];
  }
}

// ---------------- logits (fp32 exact) + xb = bf16(x) ----------------
__global__ __launch_bounds__(256) void k_logits_xb(const float* __restrict__ x,
                                                   const float* __restrict__ wst,
                                                   float* __restrict__ s, float* __restrict__ t,
                                                   unsigned int* __restrict__ xb, int N){
  __shared__ float xs[64][132];
  __shared__ float wl[2048];
  int tid = threadIdx.x;
  int n0 = blockIdx.x * 64;
  for (int i = tid; i < 2048; i += 256) wl[i] = wst[i];
  for (int i = tid; i < 2048; i += 256){
    int r = i >> 5, c4 = (i & 31) << 2;
    float4 v = make_float4(0.f, 0.f, 0.f, 0.f);
    if (n0 + r < N) v = *(const float4*)(x + (size_t)(n0 + r) * 128 + c4);
    xs[r][c4 + 0] = v.x; xs[r][c4 + 1] = v.y; xs[r][c4 + 2] = v.z; xs[r][c4 + 3] = v.w;
  }
  __syncthreads();
  int node = tid & 63, og = tid >> 6;
  int o = og * 4;
  float a0 = 0.f, a1 = 0.f, a2 = 0.f, a3 = 0.f;
  for (int k = 0; k < 128; ++k){
    float v = xs[node][k];
    a0 += v * wl[k * 16 + o + 0];
    a1 += v * wl[k * 16 + o + 1];
    a2 += v * wl[k * 16 + o + 2];
    a3 += v * wl[k * 16 + o + 3];
  }
  int n = n0 + node;
  if (n < N){
    if (o < 8){
      s[n * 8 + o + 0] = a0; s[n * 8 + o + 1] = a1;
      s[n * 8 + o + 2] = a2; s[n * 8 + o + 3] = a3;
    } else {
      int oo = o - 8;
      t[n * 8 + oo + 0] = a0; t[n * 8 + oo + 1] = a1;
      t[n * 8 + oo + 2] = a2; t[n * 8 + oo + 3] = a3;
    }
  }
  for (int i = tid; i < 4096; i += 256){
    int r = i >> 6, j = i & 63;
    int n2 = n0 + r;
    if (n2 < N)
      xb[(size_t)n2 * 64 + j] = f2bf(xs[r][2 * j]) | (f2bf(xs[r][2 * j + 1]) << 16);
  }
}

// ---------------- fused aggregation + MFMA projection ----------------
// 512 threads / 8 waves per block, 16 nodes per block (2 nodes per wave).
// Phase 1: R4-style gathers (8 dword gathers issued up-front per chunk), one-pass
// un-normalized softmax; y tile -> LDS (XOR swizzle byte^=(node&7)<<4).
// Phase 2: wave w = head w; MFMA out = y @ W1h; fused relu(+b1).W2 -> xh2.
__global__ __launch_bounds__(512, 8) void k_agg_gemm(
    const unsigned int* __restrict__ xb,   // [N][64] uint = [N][128] bf16
    const float* __restrict__ s, const float* __restrict__ t,
    const int* __restrict__ rowptr, const int* __restrict__ esrc,
    const bf16x8* __restrict__ packh,
    const float* __restrict__ b1, const float* __restrict__ W2,
    float* __restrict__ xh2, int N)
{
  __shared__ unsigned int ylds[8192];      // 16 nodes x 1024 bf16 = 32 KB
  __shared__ float lal[8][128];
  __shared__ float red[8][16];
  int tid = threadIdx.x;
  int w = tid >> 6, lane = tid & 63;
  int m0 = blockIdx.x * 16;
  int h = lane & 7;
  int es = lane >> 3;

  // ---------------- phase 1: aggregation (2 nodes per wave) ----------------
  for (int ni = 0; ni < 2; ++ni){
    int nl = w * 2 + ni;                   // local node 0..15
    int n = m0 + nl;
    float acc[16];
    #pragma unroll
    for (int i = 0; i < 16; ++i) acc[i] = 0.f;

    if (n < N){
      int row0 = rowptr[n], deg = rowptr[n + 1] - row0;
      float tn = t[(size_t)n * 8 + h];
      float sn = s[(size_t)n * 8 + h];
      float selfe = __expf(leaky(sn + tn));

      // self message (un-normalized)
      {
        unsigned int v = xb[(size_t)n * 64 + lane];
        float f0 = __uint_as_float(v << 16);
        float f1 = __uint_as_float(v & 0xffff0000u);
        #pragma unroll
        for (int hh = 0; hh < 8; ++hh){
          float a = __shfl(selfe, hh, 64);
          acc[2 * hh]     += a * f0;
          acc[2 * hh + 1] += a * f1;
        }
      }
      float dsum = (lane < 8) ? selfe : 0.f;

      float* lb = lal[w];
      for (int base = 0; base < deg; base += 8){
        float* la = lb + ((base >> 3) & 1) * 64;   // double-buffer
        int e = base + es;
        int cnt = min(8, deg - base);
        int srcl = 0;
        if (e < deg) srcl = esrc[row0 + e];
        float sv = s[(size_t)srcl * 8 + h];        // gather (srcl=0 safe for OOB)
        // broadcast src ids, issue all 8 x-gathers up-front (MLP=8)
        int sj[8];
        #pragma unroll
        for (int j = 0; j < 8; ++j) sj[j] = __shfl(srcl, j << 3, 64);
        unsigned int vv[8];
        #pragma unroll
        for (int j = 0; j < 8; ++j) vv[j] = xb[(size_t)sj[j] * 64 + lane];
        float ev = (e < deg) ? __expf(leaky(sv + tn)) : 0.f;
        dsum += ev;
        la[lane] = ev;
        #pragma unroll
        for (int j = 0; j < 8; ++j){
          if (j < cnt){
            float4 q0 = *(float4*)&la[j * 8];
            float4 q1 = *(float4*)&la[j * 8 + 4];
            float f0 = __uint_as_float(vv[j] << 16);
            float f1 = __uint_as_float(vv[j] & 0xffff0000u);
            acc[0]  += q0.x * f0; acc[1]  += q0.x * f1;
            acc[2]  += q0.y * f0; acc[3]  += q0.y * f1;
            acc[4]  += q0.z * f0; acc[5]  += q0.z * f1;
            acc[6]  += q0.w * f0; acc[7]  += q0.w * f1;
            acc[8]  += q1.x * f0; acc[9]  += q1.x * f1;
            acc[10] += q1.y * f0; acc[11] += q1.y * f1;
            acc[12] += q1.z * f0; acc[13] += q1.z * f1;
            acc[14] += q1.w * f0; acc[15] += q1.w * f1;
          }
        }
      }

      // finalize: per-head denominators, normalize
      dsum += __shfl_xor(dsum, 8, 64);
      dsum += __shfl_xor(dsum, 16, 64);
      dsum += __shfl_xor(dsum, 32, 64);
      float iden = 1.f / dsum;
      #pragma unroll
      for (int hh = 0; hh < 8; ++hh){
        float a = __shfl(iden, hh, 64);
        acc[2 * hh]     *= a;
        acc[2 * hh + 1] *= a;
      }
    }

    // write y tile to LDS (swizzled); zeros for n >= N
    #pragma unroll
    for (int hh = 0; hh < 8; ++hh){
      unsigned int p = f2bf(acc[2 * hh]) | (f2bf(acc[2 * hh + 1]) << 16);
      unsigned int byte = (unsigned)(nl * 2048 + hh * 256 + lane * 4);
      byte ^= (unsigned)((nl & 7) << 4);
      ylds[byte >> 2] = p;
    }
  }
  __syncthreads();

  // ---------------- phase 2: MFMA projection (head = wave id) + fused epilogue ----------
  int lr = lane & 15, lg = lane >> 4;
  int hD = w;
  float pnode[4] = {0.f, 0.f, 0.f, 0.f};
  bf16x8 A[4];
  #pragma unroll
  for (int kt = 0; kt < 4; ++kt){
    unsigned int byte = (unsigned)(lr * 2048 + hD * 256 + kt * 64 + lg * 16);
    byte ^= (unsigned)((lr & 7) << 4);
    A[kt] = *(const bf16x8*)((const char*)ylds + byte);
  }
  #pragma unroll
  for (int ctl = 0; ctl < 4; ++ctl){
    f32x4 acc2 = {0.f, 0.f, 0.f, 0.f};
    int pb = ((hD * 4 + ctl) * 4) * 64 + lane;
    #pragma unroll
    for (int kt = 0; kt < 4; ++kt)
      acc2 = __builtin_amdgcn_mfma_f32_16x16x32_bf16(A[kt], packh[pb + kt * 64], acc2, 0, 0, 0);
    int gc = hD * 64 + ctl * 16 + lr;
    float bb = b1[gc], wv = W2[gc];
    #pragma unroll
    for (int r = 0; r < 4; ++r){
      float o = acc2[r] + bb; o = o > 0.f ? o : 0.f;
      pnode[r] += o * wv;                  // node = m0 + lg*4 + r
    }
  }
  #pragma unroll
  for (int r = 0; r < 4; ++r){
    float v = pnode[r];
    v += __shfl_xor(v, 1, 64);
    v += __shfl_xor(v, 2, 64);
    v += __shfl_xor(v, 4, 64);
    v += __shfl_xor(v, 8, 64);
    pnode[r] = v;
  }
  if (lr == 0){
    #pragma unroll
    for (int r = 0; r < 4; ++r) red[w][lg * 4 + r] = pnode[r];
  }
  __syncthreads();
  if (tid < 16){
    int node = m0 + tid;
    if (node < N){
      float sum = 0.f;
      #pragma unroll
      for (int ww = 0; ww < 8; ++ww) sum += red[ww][tid];
      xh2[node] = sum;
    }
  }
}

// ---------------- agg2: scalar GAT layer (H=1,C=1) ----------------
__global__ void k_agg2(const float* __restrict__ xh2, const int* __restrict__ rowptr,
                       const int* __restrict__ esrc,
                       const float* __restrict__ as2p, const float* __restrict__ ad2p,
                       const float* __restrict__ b2p,
                       float* __restrict__ out, int N)
{
  int n = blockIdx.x * blockDim.x + threadIdx.x;
  if (n >= N) return;
  float a_s = as2p[0], a_d = ad2p[0], b2 = b2p[0];
  float xn = xh2[n];
  float t2 = a_d * xn;
  float w0 = __expf(leaky(a_s * xn + t2));
  float den = w0, num = w0 * xn;
  int row1 = rowptr[n + 1];
  for (int e = rowptr[n]; e < row1; ++e){
    int src = esrc[e];
    float xs2 = xh2[src];
    float w = __expf(leaky(a_s * xs2 + t2));
    den += w; num += w * xs2;
  }
  out[n] = num / den + b2;
}

extern "C" void kernel_launch(void* const* d_in, const int* in_sizes, int n_in,
                              void* d_out, int out_size, void* d_ws, size_t ws_size,
                              hipStream_t stream) {
  const float* x   = (const float*)d_in[0];
  const int*   ei  = (const int*)d_in[1];
  const float* W1  = (const float*)d_in[2];
  const float* as1 = (const float*)d_in[3];
  const float* ad1 = (const float*)d_in[4];
  const float* b1  = (const float*)d_in[5];
  const float* W2  = (const float*)d_in[6];
  const float* as2 = (const float*)d_in[7];
  const float* ad2 = (const float*)d_in[8];
  const float* b2  = (const float*)d_in[9];
  float* out = (float*)d_out;

  int N = in_sizes[0] / 128;
  int E = in_sizes[1] / 2;
  const int* src_in = ei;
  const int* dst_in = ei + E;

  char* w = (char*)d_ws;
  auto alloc = [&](size_t bytes){ void* p = (void*)w; w += (bytes + 255) & ~(size_t)255; return p; };
  unsigned int* xb   = (unsigned int*)alloc((size_t)N * 64 * 4);    // 12.8 MB
  float* s      = (float*)alloc((size_t)N * 8 * 4);
  float* t      = (float*)alloc((size_t)N * 8 * 4);
  float* xh2    = (float*)alloc((size_t)N * 4);
  int*   cnts   = (int*)alloc((size_t)2 * N * 4);                   // deg | fill
  int*   deg    = cnts;
  int*   fill   = cnts + N;
  int*   rowptr = (int*)alloc((size_t)(N + 1) * 4);
  int*   esrc   = (int*)alloc((size_t)E * 4);
  int*   tmp    = (int*)alloc((size_t)N * 4);
  int*   bsum   = (int*)alloc((size_t)1024 * 4);
  float* wst    = (float*)alloc((size_t)2048 * 4);
  bf16x8* packh = (bf16x8*)alloc((size_t)8192 * 16);

  int nb = (N + 255) / 256;

  hipMemsetAsync(cnts, 0, (size_t)2 * N * 4, stream);
  k_prep0<<<33 + (E + 255) / 256, 256, 0, stream>>>(W1, as1, ad1, wst, packh, dst_in, E, deg);
  k_logits_xb<<<(N + 63) / 64, 256, 0, stream>>>(x, wst, s, t, xb, N);
  k_scan1<<<nb, 256, 0, stream>>>(deg, tmp, bsum, N);
  k_scan2<<<1, 256, 0, stream>>>(bsum, nb);
  k_fill3<<<(E + 255) / 256, 256, 0, stream>>>(src_in, dst_in, E, tmp, bsum, rowptr, fill, esrc, N);
  k_agg_gemm<<<(N + 15) / 16, 512, 0, stream>>>(xb, s, t, rowptr, esrc, packh, b1, W2, xh2, N);
  k_agg2<<<(N + 255) / 256, 256, 0, stream>>>(xh2, rowptr, esrc, as2, ad2, b2, out, N);
}